// Round 8
// baseline (3679.742 us; speedup 1.0000x reference)
//
#include <hip/hip_runtime.h>
#include <math.h>

// Sizes fixed by the problem.
#define B_TOT 131072
#define M_N   1024
#define BS    128      // Cholesky block size
#define NBK   8        // M_N / BS

typedef float    f32x4 __attribute__((ext_vector_type(4)));
typedef _Float16 f16x8 __attribute__((ext_vector_type(8)));

// Workspace layout (bytes). Total ~16.1 MB.
enum : size_t {
    OFF_KF  = 0,                          // fp32 K (Schur-updated)  4 MB
    OFF_LF  = (size_t)4 << 20,            // fp32 L off-diag strips  4 MB
    OFF_WF  = (size_t)8 << 20,            // fp32 W = L^-1 (lower)   4 MB
    OFF_WPH = (size_t)12 << 20,           // fp16 W packed hi        2 MB
    OFF_WPL = (size_t)14 << 20,           // fp16 W packed lo        2 MB
    OFF_PF  = (size_t)16 << 20,           // fp32 params (6)
    OFF_ZT  = ((size_t)16 << 20) + 256,   // fp32 Zs_t [5][1024]     20 KB
};

__device__ __constant__ float c_zscale[5] = {0.15f, 0.1f, 0.05f, 800.0f, 20.0f};
__device__ __constant__ float c_zshift[5] = {0.0f, 0.0f, 0.0f, 600.0f, 5.0f};

// ---------------- fused: params + Zst + K = matern52 + jitter (fp32) ----------------
__global__ __launch_bounds__(256) void k_build(const float* __restrict__ log_ls,
                                               const float* __restrict__ log_var,
                                               const float* __restrict__ Zraw,
                                               float* __restrict__ Kf,
                                               float* __restrict__ pf,
                                               float* __restrict__ Zst) {
    __shared__ float ps[6];
    __shared__ float zsi[5];
    int tid = threadIdx.x;
    if (tid < 5) ps[tid] = 1.0f / (__expf(log_ls[tid]) + 1e-8f);
    if (tid == 5) ps[5] = __expf(log_var[0]);
    __syncthreads();
    int i = blockIdx.x >> 2;
    int j = (blockIdx.x & 3) * 256 + tid;
    if (tid < 5) zsi[tid] = (Zraw[i * 5 + tid] * c_zscale[tid] + c_zshift[tid]) * ps[tid];
    __syncthreads();
    float d2 = 0.0f;
#pragma unroll
    for (int d = 0; d < 5; ++d) {
        float zj = (Zraw[j * 5 + d] * c_zscale[d] + c_zshift[d]) * ps[d];
        float df = zsi[d] - zj;
        d2 += df * df;
    }
    float dd = d2 + 1e-8f;
    float dist = sqrtf(dd);
    float s = 2.23606798f * dist;
    float v = ps[5] * (1.0f + s + 1.66666667f * dd) * __expf(-s);
    if (i == j) v += 1e-4f;
    Kf[(size_t)i * M_N + j] = v;
    if (blockIdx.x < 4) {
        int m = blockIdx.x * 256 + tid;
#pragma unroll
        for (int d = 0; d < 5; ++d)
            Zst[d * M_N + m] = (Zraw[m * 5 + d] * c_zscale[d] + c_zshift[d]) * ps[d];
    }
    if (blockIdx.x == 4 && tid < 6) pf[tid] = ps[tid];
}

// ---------------- standalone Cholesky diag block kb=0 (512 thr, verified r7) ----------
__global__ __launch_bounds__(512) void kw_diag(float* __restrict__ Kf,
                                               float* __restrict__ Wf, int kb) {
    __shared__ float As[128][129];
    __shared__ float sinv[128];
    int tid = threadIdx.x;
    int r0 = kb * BS;
    for (int idx = tid; idx < BS * BS; idx += 512) {
        int rr = idx >> 7, cc = idx & 127;
        As[rr][cc] = Kf[(size_t)(r0 + rr) * M_N + r0 + cc];
    }
    __syncthreads();

    int r = tid & 127, q = tid >> 7;
    for (int p = 0; p < 16; ++p) {
        int j0 = p * 8;
        for (int j = j0; j < j0 + 8; ++j) {
            if (tid == j) {
                float d = sqrtf(As[j][j]);
                As[j][j] = d;
                sinv[j] = 1.0f / d;
            }
            __syncthreads();
            float arj = 0.0f;
            if (q == 0 && r > j) {
                arj = As[r][j] * sinv[j];
                As[r][j] = arj;
            }
            __syncthreads();
            if (q == 0 && r > j) {
#pragma unroll
                for (int c = j + 1; c < j0 + 8; ++c)
                    As[r][c] -= arj * As[c][j];
            }
        }
        __syncthreads();
        if (p < 15) {
            float a[8];
#pragma unroll
            for (int t = 0; t < 8; ++t) a[t] = As[r][j0 + t];
            for (int c = j0 + 8 + q; c < 128; c += 4) {
                if (r >= c) {
                    float s = As[r][c];
#pragma unroll
                    for (int t = 0; t < 8; ++t) s -= a[t] * As[c][j0 + t];
                    As[r][c] = s;
                }
            }
        }
        __syncthreads();
    }

    if (tid < 128) {
        int c = tid;
        for (int rb = 0; rb < 16; ++rb) {
            int r0b = rb * 8;
            if (c >= r0b + 8) continue;
            float s[8];
#pragma unroll
            for (int i = 0; i < 8; ++i) s[i] = 0.0f;
            for (int t = 0; t < r0b; ++t) {
                if (t >= c) {
                    float xt = (t == c) ? sinv[c] : As[c][t];
#pragma unroll
                    for (int i = 0; i < 8; ++i) s[i] += As[r0b + i][t] * xt;
                }
            }
            float xloc[8];
#pragma unroll
            for (int i = 0; i < 8; ++i) {
                int rr = r0b + i;
                float v = 0.0f;
                if (rr >= c) {
                    v = ((rr == c) ? 1.0f : 0.0f) - s[i];
#pragma unroll
                    for (int t2 = 0; t2 < i; ++t2) {
                        int tt = r0b + t2;
                        if (tt >= c) v -= As[rr][tt] * xloc[t2];
                    }
                    v *= sinv[rr];
                    if (rr > c) As[c][rr] = v;
                }
                xloc[i] = v;
            }
        }
    }
    __syncthreads();
    for (int idx = tid; idx < BS * BS; idx += 512) {
        int rr = idx >> 7, cc = idx & 127;
        if (rr >= cc)
            Wf[(size_t)(r0 + rr) * M_N + r0 + cc] = (rr == cc) ? sinv[rr] : As[cc][rr];
    }
}

// ---------------- strip: S(64x128) = A21[row0..] * W11^T (fp32, into LDS) -------------
static __device__ void d_strip(const float* __restrict__ Kf, const float* __restrict__ Wf,
                               int cb, int row0, float (*S)[129],
                               float (*Ast)[17], float (*Wst)[128], int tid) {
    int c = tid & 127, q = tid >> 7;
    float acc[32];
#pragma unroll
    for (int i = 0; i < 32; ++i) acc[i] = 0.0f;
    for (int tc = 0; tc < 8; ++tc) {
        int tb = tc * 16;
        __syncthreads();
        for (int idx = tid; idx < 64 * 16; idx += 256) {
            int rr = idx >> 4, tt = idx & 15;
            Ast[rr][tt] = Kf[(size_t)(row0 + rr) * M_N + cb + tb + tt];
        }
        for (int idx = tid; idx < 128 * 16; idx += 256) {
            int cc = idx >> 4, tt = idx & 15;
            Wst[tt][cc] = (tb + tt <= cc) ? Wf[(size_t)(cb + cc) * M_N + cb + tb + tt] : 0.0f;
        }
        __syncthreads();
#pragma unroll
        for (int t = 0; t < 16; ++t) {
            float w = Wst[t][c];
#pragma unroll
            for (int i = 0; i < 32; ++i) acc[i] += Ast[q * 32 + i][t] * w;
        }
    }
    __syncthreads();
#pragma unroll
    for (int i = 0; i < 32; ++i) S[q * 32 + i][c] = acc[i];
}

// ---------------- diag factor + inverse, 256 threads, As/sinv in LDS (r5-verified) -----
static __device__ void d_diag256(float (*As)[129], float* sinv,
                                 float* __restrict__ Wf, int r0, int tid) {
    int r = tid & 127, half = tid >> 7;
    for (int p = 0; p < 16; ++p) {
        int j0 = p * 8;
        for (int j = j0; j < j0 + 8; ++j) {
            if (tid == j) {
                float d = sqrtf(As[j][j]);
                As[j][j] = d;
                sinv[j] = 1.0f / d;
            }
            __syncthreads();
            float arj = 0.0f;
            if (half == 0 && r > j) {
                arj = As[r][j] * sinv[j];
                As[r][j] = arj;
            }
            __syncthreads();
            if (half == 0 && r > j) {
#pragma unroll
                for (int c = j + 1; c < j0 + 8; ++c)
                    As[r][c] -= arj * As[c][j];
            }
        }
        __syncthreads();
        if (p < 15) {
            float a[8];
#pragma unroll
            for (int t = 0; t < 8; ++t) a[t] = As[r][j0 + t];
            for (int c = j0 + 8 + half; c < 128; c += 2) {
                if (r >= c) {
                    float s = As[r][c];
#pragma unroll
                    for (int t = 0; t < 8; ++t) s -= a[t] * As[c][j0 + t];
                    As[r][c] = s;
                }
            }
        }
        __syncthreads();
    }
    // W11 = inv(L11): thread c owns column c; X[t][c] -> As[c][t] (t>c)
    if (tid < 128) {
        int c = tid;
        for (int rb = 0; rb < 16; ++rb) {
            int r0b = rb * 8;
            if (c >= r0b + 8) continue;
            float s[8];
#pragma unroll
            for (int i = 0; i < 8; ++i) s[i] = 0.0f;
            for (int t = 0; t < r0b; ++t) {
                if (t >= c) {
                    float xt = (t == c) ? sinv[c] : As[c][t];
#pragma unroll
                    for (int i = 0; i < 8; ++i) s[i] += As[r0b + i][t] * xt;
                }
            }
            float xloc[8];
#pragma unroll
            for (int i = 0; i < 8; ++i) {
                int rr = r0b + i;
                float v = 0.0f;
                if (rr >= c) {
                    v = ((rr == c) ? 1.0f : 0.0f) - s[i];
#pragma unroll
                    for (int t2 = 0; t2 < i; ++t2) {
                        int tt = r0b + t2;
                        if (tt >= c) v -= As[rr][tt] * xloc[t2];
                    }
                    v *= sinv[rr];
                    if (rr > c) As[c][rr] = v;
                }
                xloc[i] = v;
            }
        }
    }
    __syncthreads();
    for (int idx = tid; idx < BS * BS; idx += 256) {
        int rr = idx >> 7, cc = idx & 127;
        if (rr >= cc)
            Wf[(size_t)(r0 + rr) * M_N + r0 + cc] = (rr == cc) ? sinv[rr] : As[cc][rr];
    }
}

// ---------------- step kb: trailing update + NEXT diag fused into block 0 -------------
// Block 0: strips for rows base,base+64; 3 diag-region tiles -> LDS As; factor+invert.
// Blocks v>=1: tile v+2 of the triangular enumeration (by >= 2).
__global__ __launch_bounds__(256) void kw_step(float* __restrict__ Kf,
                                               float* __restrict__ Wf,
                                               float* __restrict__ Lf, int kb) {
    __shared__ float SA[64][129];
    __shared__ float SB[64][129];
    __shared__ float Ast[64][17];
    __shared__ float Wst[16][128];
    __shared__ float As[128][129];
    __shared__ float sinv[128];
    int tid = threadIdx.x;
    int base = (kb + 1) * BS;
    int cb = kb * BS;
    int tx = tid & 15, ty = tid >> 4;

    if (blockIdx.x == 0) {
        d_strip(Kf, Wf, cb, base, SA, Ast, Wst, tid);
        d_strip(Kf, Wf, cb, base + 64, SB, Ast, Wst, tid);
        __syncthreads();
        // 3 quadrants of the 128x128 diag region -> As
#pragma unroll
        for (int qq = 0; qq < 3; ++qq) {
            int qy = (qq == 0) ? 0 : 1;
            int qx = (qq == 2) ? 1 : 0;
            float (*Sy)[129] = qy ? SB : SA;
            float (*Sx)[129] = qx ? SB : SA;
            float acc[4][4];
#pragma unroll
            for (int i = 0; i < 4; ++i)
#pragma unroll
                for (int j = 0; j < 4; ++j) acc[i][j] = 0.0f;
            for (int t = 0; t < 128; ++t) {
                float a[4], b[4];
#pragma unroll
                for (int i = 0; i < 4; ++i) a[i] = Sy[ty * 4 + i][t];
#pragma unroll
                for (int j = 0; j < 4; ++j) b[j] = Sx[tx * 4 + j][t];
#pragma unroll
                for (int i = 0; i < 4; ++i)
#pragma unroll
                    for (int j = 0; j < 4; ++j) acc[i][j] = fmaf(a[i], b[j], acc[i][j]);
            }
#pragma unroll
            for (int i = 0; i < 4; ++i)
#pragma unroll
                for (int j = 0; j < 4; ++j)
                    As[qy * 64 + ty * 4 + i][qx * 64 + tx * 4 + j] =
                        Kf[(size_t)(base + qy * 64 + ty * 4 + i) * M_N +
                           base + qx * 64 + tx * 4 + j] - acc[i][j];
        }
        // persist both L strips
        for (int idx = tid; idx < 64 * 128; idx += 256) {
            int rr = idx >> 7, cc = idx & 127;
            Lf[(size_t)(base + rr) * M_N + cb + cc]      = SA[rr][cc];
            Lf[(size_t)(base + 64 + rr) * M_N + cb + cc] = SB[rr][cc];
        }
        __syncthreads();
        d_diag256(As, sinv, Wf, base, tid);
    } else {
        int vp = blockIdx.x + 2;
        int by = 0;
        while ((by + 1) * (by + 2) / 2 <= vp) ++by;
        int bx = vp - by * (by + 1) / 2;
        int gr0 = base + by * 64, gc0 = base + bx * 64;
        d_strip(Kf, Wf, cb, gr0, SA, Ast, Wst, tid);
        if (bx != by) d_strip(Kf, Wf, cb, gc0, SB, Ast, Wst, tid);
        float (*PB)[129] = (bx == by) ? SA : SB;
        __syncthreads();
        float acc[4][4];
#pragma unroll
        for (int i = 0; i < 4; ++i)
#pragma unroll
            for (int j = 0; j < 4; ++j) acc[i][j] = 0.0f;
        for (int t = 0; t < 128; ++t) {
            float a[4], b[4];
#pragma unroll
            for (int i = 0; i < 4; ++i) a[i] = SA[ty * 4 + i][t];
#pragma unroll
            for (int j = 0; j < 4; ++j) b[j] = PB[tx * 4 + j][t];
#pragma unroll
            for (int i = 0; i < 4; ++i)
#pragma unroll
                for (int j = 0; j < 4; ++j) acc[i][j] = fmaf(a[i], b[j], acc[i][j]);
        }
#pragma unroll
        for (int i = 0; i < 4; ++i)
#pragma unroll
            for (int j = 0; j < 4; ++j)
                Kf[(size_t)(gr0 + ty * 4 + i) * M_N + gc0 + tx * 4 + j] -= acc[i][j];
        if (by == bx) {
            for (int idx = tid; idx < 64 * 128; idx += 256)
                Lf[(size_t)(gr0 + (idx >> 7)) * M_N + cb + (idx & 127)] =
                    SA[idx >> 7][idx & 127];
        }
    }
}

// ---------------- trtri: single launch, fp32 (verified r7) ----------------
__global__ __launch_bounds__(512) void kw_trtri(const float* __restrict__ Lf,
                                                float* __restrict__ Wf) {
    __shared__ float Ls[128][33];
    __shared__ float Ws[32][33];
    __shared__ float Whist[6][128][33];
    __shared__ float Ps[128][33];
    int j  = blockIdx.y;
    int ct = blockIdx.x;
    int c0 = j * BS + ct * 32;
    int tid = threadIdx.x;
    int rq = tid >> 2, cq = tid & 3;

    for (int i = j + 1; i < 8; ++i) {
        float acc[8];
#pragma unroll
        for (int c = 0; c < 8; ++c) acc[c] = 0.0f;
        for (int t = j; t < i; ++t) {
            for (int ch = 0; ch < 4; ++ch) {
                int tb = t * BS + ch * 32;
                __syncthreads();
                for (int idx = tid; idx < 128 * 32; idx += 512) {
                    int rr = idx >> 5, tt = idx & 31;
                    Ls[rr][tt] = Lf[(size_t)(i * BS + rr) * M_N + tb + tt];
                }
                if (t == j) {
                    for (int idx = tid; idx < 32 * 32; idx += 512) {
                        int tt = idx >> 5, cc = idx & 31;
                        int gr = tb + tt, gc = c0 + cc;
                        Ws[tt][cc] = (gr >= gc) ? Wf[(size_t)gr * M_N + gc] : 0.0f;
                    }
                }
                __syncthreads();
                if (t == j) {
#pragma unroll
                    for (int tt = 0; tt < 32; ++tt) {
                        float l = Ls[rq][tt];
#pragma unroll
                        for (int c = 0; c < 8; ++c)
                            acc[c] = fmaf(l, Ws[tt][cq * 8 + c], acc[c]);
                    }
                } else {
                    const float (*Wh)[33] = Whist[t - j - 1];
#pragma unroll
                    for (int tt = 0; tt < 32; ++tt) {
                        float l = Ls[rq][tt];
#pragma unroll
                        for (int c = 0; c < 8; ++c)
                            acc[c] = fmaf(l, Wh[ch * 32 + tt][cq * 8 + c], acc[c]);
                    }
                }
            }
        }
        __syncthreads();
#pragma unroll
        for (int c = 0; c < 8; ++c) Ps[rq][cq * 8 + c] = acc[c];
        float a2[8];
#pragma unroll
        for (int c = 0; c < 8; ++c) a2[c] = 0.0f;
        for (int ch = 0; ch < 4; ++ch) {
            __syncthreads();
            for (int idx = tid; idx < 128 * 32; idx += 512) {
                int rr = idx >> 5, tt = idx & 31;
                Ls[rr][tt] = (rr >= ch * 32 + tt)
                           ? Wf[(size_t)(i * BS + rr) * M_N + i * BS + ch * 32 + tt] : 0.0f;
            }
            __syncthreads();
#pragma unroll
            for (int tt = 0; tt < 32; ++tt) {
                float l = Ls[rq][tt];
#pragma unroll
                for (int c = 0; c < 8; ++c)
                    a2[c] = fmaf(l, Ps[ch * 32 + tt][cq * 8 + c], a2[c]);
            }
        }
        __syncthreads();
#pragma unroll
        for (int c = 0; c < 8; ++c) {
            float v = -a2[c];
            Wf[(size_t)(i * BS + rq) * M_N + c0 + cq * 8 + c] = v;
            if (i < 7) Whist[i - j - 1][rq][cq * 8 + c] = v;
        }
        __syncthreads();
    }
}

// ---------------- pack W (fp32) into MFMA B-fragment order, fp16 hi/lo ----------------
__global__ void kw_pack(const float* __restrict__ Wf, _Float16* __restrict__ Wph,
                        _Float16* __restrict__ Wpl) {
    int T = blockIdx.x * 256 + threadIdx.x;
    int lane = T & 63, fid = T >> 6;
    int jn = fid & 63, kik = fid >> 6;
    int ki = kik & 3, kc = kik >> 2;
    int j  = jn * 16 + (lane & 15);
    int kb = kc * 128 + ki * 32 + (lane >> 4) * 8;
    f16x8 h, lo;
#pragma unroll
    for (int e = 0; e < 8; ++e) {
        int k = kb + e;
        float v = (k <= j) ? Wf[(size_t)j * M_N + k] : 0.0f;
        _Float16 hh = (_Float16)v;
        h[e]  = hh;
        lo[e] = (_Float16)(v - (float)hh);
    }
    size_t off = (size_t)fid * 512 + lane * 8;
    *(f16x8*)(Wph + off) = h;
    *(f16x8*)(Wpl + off) = lo;
}

// ---------------- main MFMA kernel: 64 rows x 1024 cols, dbuf, 1 barrier/chunk --------
__global__ __launch_bounds__(512, 1) void k_mm(const float* __restrict__ x_star,
                                               const float* __restrict__ pf,
                                               const float* __restrict__ Zst,
                                               const _Float16* __restrict__ Wph,
                                               const _Float16* __restrict__ Wpl,
                                               float* __restrict__ out, int Bq) {
    __shared__ __align__(16) char kls[2][64 * 256];  // fp16 k-tile, scc*16 swizzle
    __shared__ float red_l[64];
    int tid  = threadIdx.x;
    int slab = blockIdx.x;
    int w = tid >> 6, lane = tid & 63;
    int lrow = lane & 15, kgrp = lane >> 4;

    // staging identity: rows {srow0, srow0+32}, col-group scc (8 cols, 16B)
    int scc = tid & 15, srow0 = tid >> 4;
    int q0 = slab * 64 + srow0;
    int q1 = q0 + 32;
    int qa = (q0 < Bq) ? q0 : (Bq - 1);
    int qb = (q1 < Bq) ? q1 : (Bq - 1);
    float xa0 = x_star[(size_t)qa * 5 + 0] * pf[0];
    float xa1 = x_star[(size_t)qa * 5 + 1] * pf[1];
    float xa2 = x_star[(size_t)qa * 5 + 2] * pf[2];
    float xa3 = x_star[(size_t)qa * 5 + 3] * pf[3];
    float xa4 = x_star[(size_t)qa * 5 + 4] * pf[4];
    float xb0 = x_star[(size_t)qb * 5 + 0] * pf[0];
    float xb1 = x_star[(size_t)qb * 5 + 1] * pf[1];
    float xb2 = x_star[(size_t)qb * 5 + 2] * pf[2];
    float xb3 = x_star[(size_t)qb * 5 + 3] * pf[3];
    float xb4 = x_star[(size_t)qb * 5 + 4] * pf[4];
    float pv = pf[5];
    if (tid < 64) red_l[tid] = 0.0f;

    f32x4 acc[4][8];
#pragma unroll
    for (int mi = 0; mi < 4; ++mi)
#pragma unroll
        for (int nj = 0; nj < 8; ++nj) acc[mi][nj] = (f32x4)(0.0f);

    int jmax_w = (56 + ((w + 7) & 7)) * 16 + 15;   // jng = 8nj + ((w+nj)&7)
    int swz = (scc * 16) ^ ((srow0 & 15) << 4);    // (srow0+32)&15 == srow0&15
    int soff0 = srow0 * 256 + swz;
    int soff1 = (srow0 + 32) * 256 + swz;

    auto stage = [&](int kc, char* buf) {
        f16x8 h0, h1;
#pragma unroll
        for (int bb = 0; bb < 2; ++bb) {
            int lb = kc * 128 + scc * 8 + bb * 4;
            float z0[4], z1[4], z2[4], z3[4], z4[4];
            *(float4*)z0 = *(const float4*)&Zst[lb];
            *(float4*)z1 = *(const float4*)&Zst[M_N + lb];
            *(float4*)z2 = *(const float4*)&Zst[2 * M_N + lb];
            *(float4*)z3 = *(const float4*)&Zst[3 * M_N + lb];
            *(float4*)z4 = *(const float4*)&Zst[4 * M_N + lb];
#pragma unroll
            for (int e = 0; e < 4; ++e) {
                float dx0 = xa0 - z0[e], dx1 = xa1 - z1[e], dx2 = xa2 - z2[e],
                      dx3 = xa3 - z3[e], dx4 = xa4 - z4[e];
                float d2 = dx0 * dx0 + dx1 * dx1 + dx2 * dx2 + dx3 * dx3 + dx4 * dx4;
                float ddv = d2 + 1e-8f;
                float dist = sqrtf(ddv);
                float sv = 2.23606798f * dist;
                h0[bb * 4 + e] = (_Float16)(pv * (1.0f + sv + 1.66666667f * ddv) * __expf(-sv));
                float ex0 = xb0 - z0[e], ex1 = xb1 - z1[e], ex2 = xb2 - z2[e],
                      ex3 = xb3 - z3[e], ex4 = xb4 - z4[e];
                float e2 = ex0 * ex0 + ex1 * ex1 + ex2 * ex2 + ex3 * ex3 + ex4 * ex4;
                float eev = e2 + 1e-8f;
                float edist = sqrtf(eev);
                float esv = 2.23606798f * edist;
                h1[bb * 4 + e] = (_Float16)(pv * (1.0f + esv + 1.66666667f * eev) * __expf(-esv));
            }
        }
        *(f16x8*)(&buf[soff0]) = h0;
        *(f16x8*)(&buf[soff1]) = h1;
    };

    stage(0, kls[0]);
    __syncthreads();

    for (int kc = 0; kc < 8; ++kc) {
        // stage next chunk into the other buffer (safe: fully read before last barrier)
        if (kc < 7) stage(kc + 1, kls[(kc + 1) & 1]);
        const char* cur = kls[kc & 1];
        for (int ki = 0; ki < 4; ++ki) {
            int kmin = kc * 128 + ki * 32;
            if (kmin > jmax_w) break;            // wave-uniform (jng monotone in nj)
            f16x8 A_[4];
#pragma unroll
            for (int mi = 0; mi < 4; ++mi) {
                int row = mi * 16 + lrow;
                int cb  = ki * 64 + kgrp * 16;
                A_[mi] = *(const f16x8*)(&cur[row * 256 + (cb ^ ((row & 15) << 4))]);
            }
#pragma unroll
            for (int nj = 0; nj < 8; ++nj) {
                int jng = nj * 8 + ((w + nj) & 7);    // balanced col interleave
                if (kmin > jng * 16 + 15) continue;   // all-zero W fragment
                size_t fo = ((size_t)((kc * 4 + ki) * 64 + jng)) * 512 + lane * 8;
                f16x8 Bh = *(const f16x8*)(Wph + fo);
                f16x8 Bl = *(const f16x8*)(Wpl + fo);
#pragma unroll
                for (int mi = 0; mi < 4; ++mi) {
                    acc[mi][nj] = __builtin_amdgcn_mfma_f32_16x16x32_f16(A_[mi], Bh, acc[mi][nj], 0, 0, 0);
                    acc[mi][nj] = __builtin_amdgcn_mfma_f32_16x16x32_f16(A_[mi], Bl, acc[mi][nj], 0, 0, 0);
                }
            }
        }
        __syncthreads();   // cur reads done (next overwrite) + next-buf writes visible
    }

    // epilogue: red[row] += y^2 ; C layout: row = mi*16 + kgrp*4 + q, col = jng*16 + lrow
#pragma unroll
    for (int mi = 0; mi < 4; ++mi) {
#pragma unroll
        for (int q = 0; q < 4; ++q) {
            float s = 0.0f;
#pragma unroll
            for (int nj = 0; nj < 8; ++nj) s = fmaf(acc[mi][nj][q], acc[mi][nj][q], s);
            s += __shfl_xor(s, 1);
            s += __shfl_xor(s, 2);
            s += __shfl_xor(s, 4);
            s += __shfl_xor(s, 8);
            if (lrow == 0) atomicAdd(&red_l[mi * 16 + kgrp * 4 + q], s);
        }
    }
    __syncthreads();
    if (tid < 64) {
        int b = slab * 64 + tid;
        if (b < Bq) out[b] = sqrtf(fmaxf(pv - red_l[tid], 1e-6f));
    }
}

extern "C" void kernel_launch(void* const* d_in, const int* in_sizes, int n_in,
                              void* d_out, int out_size, void* d_ws, size_t ws_size,
                              hipStream_t stream) {
    const float* x_star  = (const float*)d_in[0];
    const float* log_ls  = (const float*)d_in[1];
    const float* log_var = (const float*)d_in[2];
    const float* Z_raw   = (const float*)d_in[3];
    float* out = (float*)d_out;
    int Bq = in_sizes[0] / 5;

    char* ws = (char*)d_ws;
    float*     Kf  = (float*)(ws + OFF_KF);
    float*     Lf  = (float*)(ws + OFF_LF);
    float*     Wf  = (float*)(ws + OFF_WF);
    _Float16*  Wph = (_Float16*)(ws + OFF_WPH);
    _Float16*  Wpl = (_Float16*)(ws + OFF_WPL);
    float*     pf  = (float*)(ws + OFF_PF);
    float*     Zst = (float*)(ws + OFF_ZT);

    k_build<<<4096, 256, 0, stream>>>(log_ls, log_var, Z_raw, Kf, pf, Zst);
    kw_diag<<<1, 512, 0, stream>>>(Kf, Wf, 0);

    for (int kb = 0; kb < NBK - 1; ++kb) {
        int nt = (NBK - 1 - kb) * 2;                 // 14,12,10,8,6,4,2
        int grid = nt * (nt + 1) / 2 - 2;            // block 0 absorbs 3 diag tiles
        kw_step<<<grid, 256, 0, stream>>>(Kf, Wf, Lf, kb);
    }

    kw_trtri<<<dim3(4, 7), 512, 0, stream>>>(Lf, Wf);
    kw_pack<<<512, 256, 0, stream>>>(Wf, Wph, Wpl);

    int slabs = (Bq + 63) / 64;
    k_mm<<<slabs, 512, 0, stream>>>(x_star, pf, Zst, Wph, Wpl, out, Bq);
}

// Round 9
// 3590.669 us; speedup vs baseline: 1.0248x; 1.0248x over previous
//
#include <hip/hip_runtime.h>
#include <math.h>

// Sizes fixed by the problem.
#define B_TOT 131072
#define M_N   1024
#define BS    128      // Cholesky block size
#define NBK   8        // M_N / BS

typedef float    f32x4 __attribute__((ext_vector_type(4)));
typedef _Float16 f16x8 __attribute__((ext_vector_type(8)));

// Workspace layout (bytes). Chain ~18 MB; Apack (optional) at 32 MB, 268 MB.
enum : size_t {
    OFF_KF  = 0,                          // fp32 K (Schur-updated)  4 MB
    OFF_LF  = (size_t)4 << 20,            // fp32 L off-diag strips  4 MB
    OFF_WF  = (size_t)8 << 20,            // fp32 W = L^-1 (lower)   4 MB
    OFF_WPH = (size_t)12 << 20,           // fp16 W packed hi        2 MB
    OFF_WPL = (size_t)14 << 20,           // fp16 W packed lo        2 MB
    OFF_PF  = (size_t)16 << 20,           // fp32 params (6)
    OFF_ZT  = ((size_t)16 << 20) + 256,   // fp32 Zs_t [5][1024]     20 KB
    OFF_RED = (size_t)17 << 20,           // f32 redp[2][B]          1 MB
    OFF_AP  = (size_t)32 << 20,           // fp16 k_xZ in A-frag layout (268 MB)
};

__device__ __constant__ float c_zscale[5] = {0.15f, 0.1f, 0.05f, 800.0f, 20.0f};
__device__ __constant__ float c_zshift[5] = {0.0f, 0.0f, 0.0f, 600.0f, 5.0f};

// ---------------- fused: params + Zst + K = matern52 + jitter (fp32) ----------------
__global__ __launch_bounds__(256) void k_build(const float* __restrict__ log_ls,
                                               const float* __restrict__ log_var,
                                               const float* __restrict__ Zraw,
                                               float* __restrict__ Kf,
                                               float* __restrict__ pf,
                                               float* __restrict__ Zst) {
    __shared__ float ps[6];
    __shared__ float zsi[5];
    int tid = threadIdx.x;
    if (tid < 5) ps[tid] = 1.0f / (__expf(log_ls[tid]) + 1e-8f);
    if (tid == 5) ps[5] = __expf(log_var[0]);
    __syncthreads();
    int i = blockIdx.x >> 2;
    int j = (blockIdx.x & 3) * 256 + tid;
    if (tid < 5) zsi[tid] = (Zraw[i * 5 + tid] * c_zscale[tid] + c_zshift[tid]) * ps[tid];
    __syncthreads();
    float d2 = 0.0f;
#pragma unroll
    for (int d = 0; d < 5; ++d) {
        float zj = (Zraw[j * 5 + d] * c_zscale[d] + c_zshift[d]) * ps[d];
        float df = zsi[d] - zj;
        d2 += df * df;
    }
    float dd = d2 + 1e-8f;
    float dist = sqrtf(dd);
    float s = 2.23606798f * dist;
    float v = ps[5] * (1.0f + s + 1.66666667f * dd) * __expf(-s);
    if (i == j) v += 1e-4f;
    Kf[(size_t)i * M_N + j] = v;
    if (blockIdx.x < 4) {
        int m = blockIdx.x * 256 + tid;
#pragma unroll
        for (int d = 0; d < 5; ++d)
            Zst[d * M_N + m] = (Zraw[m * 5 + d] * c_zscale[d] + c_zshift[d]) * ps[d];
    }
    if (blockIdx.x == 4 && tid < 6) pf[tid] = ps[tid];
}

// ---------------- k_gen: k_xZ in MFMA-A-fragment fp16 layout ----------------
// fid = (slab*32 + kk)*4 + mi ; lane l elem e -> row slab*64+mi*16+(l&15),
// k = kk*32 + (l>>4)*8 + e.  Write 16B/lane coalesced.
__global__ __launch_bounds__(256) void k_gen(const float* __restrict__ x_star,
                                             const float* __restrict__ pf,
                                             const float* __restrict__ Zst,
                                             _Float16* __restrict__ Ap, int Bq) {
    int tid = threadIdx.x;
    int lane = tid & 63;
    int fid = blockIdx.x * 4 + (tid >> 6);
    int mi = fid & 3, kk = (fid >> 2) & 31, slab = fid >> 7;
    int row = slab * 64 + mi * 16 + (lane & 15);
    int k0 = kk * 32 + (lane >> 4) * 8;
    int rc = (row < Bq) ? row : (Bq - 1);
    float x0 = x_star[(size_t)rc * 5 + 0] * pf[0];
    float x1 = x_star[(size_t)rc * 5 + 1] * pf[1];
    float x2 = x_star[(size_t)rc * 5 + 2] * pf[2];
    float x3 = x_star[(size_t)rc * 5 + 3] * pf[3];
    float x4 = x_star[(size_t)rc * 5 + 4] * pf[4];
    float pv = pf[5];
    float z0[8], z1[8], z2[8], z3[8], z4[8];
    *(float4*)&z0[0] = *(const float4*)&Zst[k0];
    *(float4*)&z0[4] = *(const float4*)&Zst[k0 + 4];
    *(float4*)&z1[0] = *(const float4*)&Zst[M_N + k0];
    *(float4*)&z1[4] = *(const float4*)&Zst[M_N + k0 + 4];
    *(float4*)&z2[0] = *(const float4*)&Zst[2 * M_N + k0];
    *(float4*)&z2[4] = *(const float4*)&Zst[2 * M_N + k0 + 4];
    *(float4*)&z3[0] = *(const float4*)&Zst[3 * M_N + k0];
    *(float4*)&z3[4] = *(const float4*)&Zst[3 * M_N + k0 + 4];
    *(float4*)&z4[0] = *(const float4*)&Zst[4 * M_N + k0];
    *(float4*)&z4[4] = *(const float4*)&Zst[4 * M_N + k0 + 4];
    f16x8 h;
#pragma unroll
    for (int e = 0; e < 8; ++e) {
        float dx0 = x0 - z0[e], dx1 = x1 - z1[e], dx2 = x2 - z2[e],
              dx3 = x3 - z3[e], dx4 = x4 - z4[e];
        float d2 = dx0 * dx0 + dx1 * dx1 + dx2 * dx2 + dx3 * dx3 + dx4 * dx4;
        float dd = d2 + 1e-8f;
        float dist = sqrtf(dd);
        float sv = 2.23606798f * dist;
        h[e] = (_Float16)(pv * (1.0f + sv + 1.66666667f * dd) * __expf(-sv));
    }
    *(f16x8*)(&Ap[(size_t)fid * 512 + lane * 8]) = h;
}

// ---------------- standalone Cholesky diag block kb=0 (grid padded to 64) -------------
__global__ __launch_bounds__(512) void kw_diag(float* __restrict__ Kf,
                                               float* __restrict__ Wf, int kb) {
    if (blockIdx.x) return;   // grid padding (tiny-grid stall mitigation)
    __shared__ float As[128][129];
    __shared__ float sinv[128];
    int tid = threadIdx.x;
    int r0 = kb * BS;
    for (int idx = tid; idx < BS * BS; idx += 512) {
        int rr = idx >> 7, cc = idx & 127;
        As[rr][cc] = Kf[(size_t)(r0 + rr) * M_N + r0 + cc];
    }
    __syncthreads();

    int r = tid & 127, q = tid >> 7;
    for (int p = 0; p < 16; ++p) {
        int j0 = p * 8;
        for (int j = j0; j < j0 + 8; ++j) {
            if (tid == j) {
                float d = sqrtf(As[j][j]);
                As[j][j] = d;
                sinv[j] = 1.0f / d;
            }
            __syncthreads();
            float arj = 0.0f;
            if (q == 0 && r > j) {
                arj = As[r][j] * sinv[j];
                As[r][j] = arj;
            }
            __syncthreads();
            if (q == 0 && r > j) {
#pragma unroll
                for (int c = j + 1; c < j0 + 8; ++c)
                    As[r][c] -= arj * As[c][j];
            }
        }
        __syncthreads();
        if (p < 15) {
            float a[8];
#pragma unroll
            for (int t = 0; t < 8; ++t) a[t] = As[r][j0 + t];
            for (int c = j0 + 8 + q; c < 128; c += 4) {
                if (r >= c) {
                    float s = As[r][c];
#pragma unroll
                    for (int t = 0; t < 8; ++t) s -= a[t] * As[c][j0 + t];
                    As[r][c] = s;
                }
            }
        }
        __syncthreads();
    }

    if (tid < 128) {
        int c = tid;
        for (int rb = 0; rb < 16; ++rb) {
            int r0b = rb * 8;
            if (c >= r0b + 8) continue;
            float s[8];
#pragma unroll
            for (int i = 0; i < 8; ++i) s[i] = 0.0f;
            for (int t = 0; t < r0b; ++t) {
                if (t >= c) {
                    float xt = (t == c) ? sinv[c] : As[c][t];
#pragma unroll
                    for (int i = 0; i < 8; ++i) s[i] += As[r0b + i][t] * xt;
                }
            }
            float xloc[8];
#pragma unroll
            for (int i = 0; i < 8; ++i) {
                int rr = r0b + i;
                float v = 0.0f;
                if (rr >= c) {
                    v = ((rr == c) ? 1.0f : 0.0f) - s[i];
#pragma unroll
                    for (int t2 = 0; t2 < i; ++t2) {
                        int tt = r0b + t2;
                        if (tt >= c) v -= As[rr][tt] * xloc[t2];
                    }
                    v *= sinv[rr];
                    if (rr > c) As[c][rr] = v;
                }
                xloc[i] = v;
            }
        }
    }
    __syncthreads();
    for (int idx = tid; idx < BS * BS; idx += 512) {
        int rr = idx >> 7, cc = idx & 127;
        if (rr >= cc)
            Wf[(size_t)(r0 + rr) * M_N + r0 + cc] = (rr == cc) ? sinv[rr] : As[cc][rr];
    }
}

// ---------------- strip: S(64x128) = A21[row0..] * W11^T (fp32, into LDS) -------------
static __device__ void d_strip(const float* __restrict__ Kf, const float* __restrict__ Wf,
                               int cb, int row0, float (*S)[129],
                               float (*Ast)[17], float (*Wst)[128], int tid) {
    int c = tid & 127, q = tid >> 7;
    float acc[32];
#pragma unroll
    for (int i = 0; i < 32; ++i) acc[i] = 0.0f;
    for (int tc = 0; tc < 8; ++tc) {
        int tb = tc * 16;
        __syncthreads();
        for (int idx = tid; idx < 64 * 16; idx += 256) {
            int rr = idx >> 4, tt = idx & 15;
            Ast[rr][tt] = Kf[(size_t)(row0 + rr) * M_N + cb + tb + tt];
        }
        for (int idx = tid; idx < 128 * 16; idx += 256) {
            int cc = idx >> 4, tt = idx & 15;
            Wst[tt][cc] = (tb + tt <= cc) ? Wf[(size_t)(cb + cc) * M_N + cb + tb + tt] : 0.0f;
        }
        __syncthreads();
#pragma unroll
        for (int t = 0; t < 16; ++t) {
            float w = Wst[t][c];
#pragma unroll
            for (int i = 0; i < 32; ++i) acc[i] += Ast[q * 32 + i][t] * w;
        }
    }
    __syncthreads();
#pragma unroll
    for (int i = 0; i < 32; ++i) S[q * 32 + i][c] = acc[i];
}

// ---------------- diag factor + inverse, 256 threads (r5-verified) ----------------
static __device__ void d_diag256(float (*As)[129], float* sinv,
                                 float* __restrict__ Wf, int r0, int tid) {
    int r = tid & 127, half = tid >> 7;
    for (int p = 0; p < 16; ++p) {
        int j0 = p * 8;
        for (int j = j0; j < j0 + 8; ++j) {
            if (tid == j) {
                float d = sqrtf(As[j][j]);
                As[j][j] = d;
                sinv[j] = 1.0f / d;
            }
            __syncthreads();
            float arj = 0.0f;
            if (half == 0 && r > j) {
                arj = As[r][j] * sinv[j];
                As[r][j] = arj;
            }
            __syncthreads();
            if (half == 0 && r > j) {
#pragma unroll
                for (int c = j + 1; c < j0 + 8; ++c)
                    As[r][c] -= arj * As[c][j];
            }
        }
        __syncthreads();
        if (p < 15) {
            float a[8];
#pragma unroll
            for (int t = 0; t < 8; ++t) a[t] = As[r][j0 + t];
            for (int c = j0 + 8 + half; c < 128; c += 2) {
                if (r >= c) {
                    float s = As[r][c];
#pragma unroll
                    for (int t = 0; t < 8; ++t) s -= a[t] * As[c][j0 + t];
                    As[r][c] = s;
                }
            }
        }
        __syncthreads();
    }
    if (tid < 128) {
        int c = tid;
        for (int rb = 0; rb < 16; ++rb) {
            int r0b = rb * 8;
            if (c >= r0b + 8) continue;
            float s[8];
#pragma unroll
            for (int i = 0; i < 8; ++i) s[i] = 0.0f;
            for (int t = 0; t < r0b; ++t) {
                if (t >= c) {
                    float xt = (t == c) ? sinv[c] : As[c][t];
#pragma unroll
                    for (int i = 0; i < 8; ++i) s[i] += As[r0b + i][t] * xt;
                }
            }
            float xloc[8];
#pragma unroll
            for (int i = 0; i < 8; ++i) {
                int rr = r0b + i;
                float v = 0.0f;
                if (rr >= c) {
                    v = ((rr == c) ? 1.0f : 0.0f) - s[i];
#pragma unroll
                    for (int t2 = 0; t2 < i; ++t2) {
                        int tt = r0b + t2;
                        if (tt >= c) v -= As[rr][tt] * xloc[t2];
                    }
                    v *= sinv[rr];
                    if (rr > c) As[c][rr] = v;
                }
                xloc[i] = v;
            }
        }
    }
    __syncthreads();
    for (int idx = tid; idx < BS * BS; idx += 256) {
        int rr = idx >> 7, cc = idx & 127;
        if (rr >= cc)
            Wf[(size_t)(r0 + rr) * M_N + r0 + cc] = (rr == cc) ? sinv[rr] : As[cc][rr];
    }
}

// ---------------- step kb: trailing update + NEXT diag fused into block 0 -------------
__global__ __launch_bounds__(256) void kw_step(float* __restrict__ Kf,
                                               float* __restrict__ Wf,
                                               float* __restrict__ Lf, int kb) {
    __shared__ float SA[64][129];
    __shared__ float SB[64][129];
    __shared__ float Ast[64][17];
    __shared__ float Wst[16][128];
    __shared__ float As[128][129];
    __shared__ float sinv[128];
    int tid = threadIdx.x;
    int base = (kb + 1) * BS;
    int cb = kb * BS;
    int tx = tid & 15, ty = tid >> 4;
    int nt = (NBK - 1 - kb) * 2;
    int ntile = nt * (nt + 1) / 2;

    if (blockIdx.x == 0) {
        d_strip(Kf, Wf, cb, base, SA, Ast, Wst, tid);
        d_strip(Kf, Wf, cb, base + 64, SB, Ast, Wst, tid);
        __syncthreads();
#pragma unroll
        for (int qq = 0; qq < 3; ++qq) {
            int qy = (qq == 0) ? 0 : 1;
            int qx = (qq == 2) ? 1 : 0;
            float (*Sy)[129] = qy ? SB : SA;
            float (*Sx)[129] = qx ? SB : SA;
            float acc[4][4];
#pragma unroll
            for (int i = 0; i < 4; ++i)
#pragma unroll
                for (int j = 0; j < 4; ++j) acc[i][j] = 0.0f;
            for (int t = 0; t < 128; ++t) {
                float a[4], b[4];
#pragma unroll
                for (int i = 0; i < 4; ++i) a[i] = Sy[ty * 4 + i][t];
#pragma unroll
                for (int j = 0; j < 4; ++j) b[j] = Sx[tx * 4 + j][t];
#pragma unroll
                for (int i = 0; i < 4; ++i)
#pragma unroll
                    for (int j = 0; j < 4; ++j) acc[i][j] = fmaf(a[i], b[j], acc[i][j]);
            }
#pragma unroll
            for (int i = 0; i < 4; ++i)
#pragma unroll
                for (int j = 0; j < 4; ++j)
                    As[qy * 64 + ty * 4 + i][qx * 64 + tx * 4 + j] =
                        Kf[(size_t)(base + qy * 64 + ty * 4 + i) * M_N +
                           base + qx * 64 + tx * 4 + j] - acc[i][j];
        }
        for (int idx = tid; idx < 64 * 128; idx += 256) {
            int rr = idx >> 7, cc = idx & 127;
            Lf[(size_t)(base + rr) * M_N + cb + cc]      = SA[rr][cc];
            Lf[(size_t)(base + 64 + rr) * M_N + cb + cc] = SB[rr][cc];
        }
        __syncthreads();
        d_diag256(As, sinv, Wf, base, tid);
    } else {
        int vp = blockIdx.x + 2;
        if (vp >= ntile) return;   // grid padding
        int by = 0;
        while ((by + 1) * (by + 2) / 2 <= vp) ++by;
        int bx = vp - by * (by + 1) / 2;
        int gr0 = base + by * 64, gc0 = base + bx * 64;
        d_strip(Kf, Wf, cb, gr0, SA, Ast, Wst, tid);
        if (bx != by) d_strip(Kf, Wf, cb, gc0, SB, Ast, Wst, tid);
        float (*PB)[129] = (bx == by) ? SA : SB;
        __syncthreads();
        float acc[4][4];
#pragma unroll
        for (int i = 0; i < 4; ++i)
#pragma unroll
            for (int j = 0; j < 4; ++j) acc[i][j] = 0.0f;
        for (int t = 0; t < 128; ++t) {
            float a[4], b[4];
#pragma unroll
            for (int i = 0; i < 4; ++i) a[i] = SA[ty * 4 + i][t];
#pragma unroll
            for (int j = 0; j < 4; ++j) b[j] = PB[tx * 4 + j][t];
#pragma unroll
            for (int i = 0; i < 4; ++i)
#pragma unroll
                for (int j = 0; j < 4; ++j) acc[i][j] = fmaf(a[i], b[j], acc[i][j]);
        }
#pragma unroll
        for (int i = 0; i < 4; ++i)
#pragma unroll
            for (int j = 0; j < 4; ++j)
                Kf[(size_t)(gr0 + ty * 4 + i) * M_N + gc0 + tx * 4 + j] -= acc[i][j];
        if (by == bx) {
            for (int idx = tid; idx < 64 * 128; idx += 256)
                Lf[(size_t)(gr0 + (idx >> 7)) * M_N + cb + (idx & 127)] =
                    SA[idx >> 7][idx & 127];
        }
    }
}

// ---------------- trtri: single launch, fp32 (verified r7) ----------------
__global__ __launch_bounds__(512) void kw_trtri(const float* __restrict__ Lf,
                                                float* __restrict__ Wf) {
    __shared__ float Ls[128][33];
    __shared__ float Ws[32][33];
    __shared__ float Whist[6][128][33];
    __shared__ float Ps[128][33];
    int j  = blockIdx.y;
    int ct = blockIdx.x;
    int c0 = j * BS + ct * 32;
    int tid = threadIdx.x;
    int rq = tid >> 2, cq = tid & 3;

    for (int i = j + 1; i < 8; ++i) {
        float acc[8];
#pragma unroll
        for (int c = 0; c < 8; ++c) acc[c] = 0.0f;
        for (int t = j; t < i; ++t) {
            for (int ch = 0; ch < 4; ++ch) {
                int tb = t * BS + ch * 32;
                __syncthreads();
                for (int idx = tid; idx < 128 * 32; idx += 512) {
                    int rr = idx >> 5, tt = idx & 31;
                    Ls[rr][tt] = Lf[(size_t)(i * BS + rr) * M_N + tb + tt];
                }
                if (t == j) {
                    for (int idx = tid; idx < 32 * 32; idx += 512) {
                        int tt = idx >> 5, cc = idx & 31;
                        int gr = tb + tt, gc = c0 + cc;
                        Ws[tt][cc] = (gr >= gc) ? Wf[(size_t)gr * M_N + gc] : 0.0f;
                    }
                }
                __syncthreads();
                if (t == j) {
#pragma unroll
                    for (int tt = 0; tt < 32; ++tt) {
                        float l = Ls[rq][tt];
#pragma unroll
                        for (int c = 0; c < 8; ++c)
                            acc[c] = fmaf(l, Ws[tt][cq * 8 + c], acc[c]);
                    }
                } else {
                    const float (*Wh)[33] = Whist[t - j - 1];
#pragma unroll
                    for (int tt = 0; tt < 32; ++tt) {
                        float l = Ls[rq][tt];
#pragma unroll
                        for (int c = 0; c < 8; ++c)
                            acc[c] = fmaf(l, Wh[ch * 32 + tt][cq * 8 + c], acc[c]);
                    }
                }
            }
        }
        __syncthreads();
#pragma unroll
        for (int c = 0; c < 8; ++c) Ps[rq][cq * 8 + c] = acc[c];
        float a2[8];
#pragma unroll
        for (int c = 0; c < 8; ++c) a2[c] = 0.0f;
        for (int ch = 0; ch < 4; ++ch) {
            __syncthreads();
            for (int idx = tid; idx < 128 * 32; idx += 512) {
                int rr = idx >> 5, tt = idx & 31;
                Ls[rr][tt] = (rr >= ch * 32 + tt)
                           ? Wf[(size_t)(i * BS + rr) * M_N + i * BS + ch * 32 + tt] : 0.0f;
            }
            __syncthreads();
#pragma unroll
            for (int tt = 0; tt < 32; ++tt) {
                float l = Ls[rq][tt];
#pragma unroll
                for (int c = 0; c < 8; ++c)
                    a2[c] = fmaf(l, Ps[ch * 32 + tt][cq * 8 + c], a2[c]);
            }
        }
        __syncthreads();
#pragma unroll
        for (int c = 0; c < 8; ++c) {
            float v = -a2[c];
            Wf[(size_t)(i * BS + rq) * M_N + c0 + cq * 8 + c] = v;
            if (i < 7) Whist[i - j - 1][rq][cq * 8 + c] = v;
        }
        __syncthreads();
    }
}

// ---------------- pack W (fp32) into MFMA B-fragment order, fp16 hi/lo ----------------
__global__ void kw_pack(const float* __restrict__ Wf, _Float16* __restrict__ Wph,
                        _Float16* __restrict__ Wpl) {
    int T = blockIdx.x * 256 + threadIdx.x;
    int lane = T & 63, fid = T >> 6;
    int jn = fid & 63, kik = fid >> 6;
    int ki = kik & 3, kc = kik >> 2;
    int j  = jn * 16 + (lane & 15);
    int kb = kc * 128 + ki * 32 + (lane >> 4) * 8;
    f16x8 h, lo;
#pragma unroll
    for (int e = 0; e < 8; ++e) {
        int k = kb + e;
        float v = (k <= j) ? Wf[(size_t)j * M_N + k] : 0.0f;
        _Float16 hh = (_Float16)v;
        h[e]  = hh;
        lo[e] = (_Float16)(v - (float)hh);
    }
    size_t off = (size_t)fid * 512 + lane * 8;
    *(f16x8*)(Wph + off) = h;
    *(f16x8*)(Wpl + off) = lo;
}

// ---------------- k_mm: PURE barrier-free GEMM, 64 rows x 512 cols per block ----------
__global__ __launch_bounds__(512) void k_mm(const _Float16* __restrict__ Ap,
                                            const _Float16* __restrict__ Wph,
                                            const _Float16* __restrict__ Wpl,
                                            float* __restrict__ redp, int Bq) {
    __shared__ float red_l[64];
    int tid  = threadIdx.x;
    int slab = blockIdx.x, pp = blockIdx.y;
    int w = tid >> 6, lane = tid & 63;
    int lrow = lane & 15, kgrp = lane >> 4;
    if (tid < 64) red_l[tid] = 0.0f;
    __syncthreads();

    f32x4 acc[4][4];
#pragma unroll
    for (int mi = 0; mi < 4; ++mi)
#pragma unroll
        for (int nj = 0; nj < 4; ++nj) acc[mi][nj] = (f32x4)(0.0f);

    int jmax_w = (pp * 32 + 24 + ((w + 3) & 7)) * 16 + 15;   // jng = pp*32+8nj+((w+nj)&7)
    const _Float16* Abase = Ap + (size_t)slab * 128 * 512 + lane * 8;
    const _Float16* Whb = Wph + lane * 8;
    const _Float16* Wlb = Wpl + lane * 8;

    for (int kt = 0; kt < 32; ++kt) {
        int kmin = kt * 32;
        if (kmin > jmax_w) break;            // wave-uniform
        f16x8 A_[4];
#pragma unroll
        for (int mi = 0; mi < 4; ++mi)
            A_[mi] = *(const f16x8*)(Abase + (size_t)(kt * 4 + mi) * 512);
#pragma unroll
        for (int nj = 0; nj < 4; ++nj) {
            int jng = pp * 32 + nj * 8 + ((w + nj) & 7);   // balanced col interleave
            if (kmin > jng * 16 + 15) continue;            // all-zero W fragment
            size_t fo = (size_t)(kt * 64 + jng) * 512;
            f16x8 Bh = *(const f16x8*)(Whb + fo);
            f16x8 Bl = *(const f16x8*)(Wlb + fo);
#pragma unroll
            for (int mi = 0; mi < 4; ++mi) {
                acc[mi][nj] = __builtin_amdgcn_mfma_f32_16x16x32_f16(A_[mi], Bh, acc[mi][nj], 0, 0, 0);
                acc[mi][nj] = __builtin_amdgcn_mfma_f32_16x16x32_f16(A_[mi], Bl, acc[mi][nj], 0, 0, 0);
            }
        }
    }

    // epilogue: red[row] += y^2 ; C layout: row = mi*16 + kgrp*4 + q, col = jng*16 + lrow
#pragma unroll
    for (int mi = 0; mi < 4; ++mi) {
#pragma unroll
        for (int q = 0; q < 4; ++q) {
            float s = 0.0f;
#pragma unroll
            for (int nj = 0; nj < 4; ++nj) s = fmaf(acc[mi][nj][q], acc[mi][nj][q], s);
            s += __shfl_xor(s, 1);
            s += __shfl_xor(s, 2);
            s += __shfl_xor(s, 4);
            s += __shfl_xor(s, 8);
            if (lrow == 0) atomicAdd(&red_l[mi * 16 + kgrp * 4 + q], s);
        }
    }
    __syncthreads();
    if (tid < 64) {
        int b = slab * 64 + tid;
        if (b < Bq) redp[(size_t)pp * Bq + b] = red_l[tid];
    }
}

// ---------------- final combine ----------------
__global__ void k_fin(const float* __restrict__ redp, const float* __restrict__ pf,
                      float* __restrict__ out, int Bq) {
    int b = blockIdx.x * 256 + threadIdx.x;
    if (b < Bq) {
        float red = redp[b] + redp[(size_t)Bq + b];
        out[b] = sqrtf(fmaxf(pf[5] - red, 1e-6f));
    }
}

// ---------------- fallback fused k_mm (r6 structure, fp16) — only if ws too small -----
__global__ __launch_bounds__(512, 1) void k_mm_fused(const float* __restrict__ x_star,
                                                     const float* __restrict__ pf,
                                                     const float* __restrict__ Zst,
                                                     const _Float16* __restrict__ Wph,
                                                     const _Float16* __restrict__ Wpl,
                                                     float* __restrict__ out, int Bq) {
    __shared__ __align__(16) char kls[32 * 256];
    __shared__ float red_l[32];
    int tid  = threadIdx.x;
    int slab = blockIdx.x;
    int w = tid >> 6, lane = tid & 63;
    int lrow = lane & 15, kgrp = lane >> 4;
    int srow = tid >> 4, scc = tid & 15;
    int qrow = slab * 32 + srow;
    int qc = (qrow < Bq) ? qrow : (Bq - 1);
    float xv0 = x_star[(size_t)qc * 5 + 0] * pf[0];
    float xv1 = x_star[(size_t)qc * 5 + 1] * pf[1];
    float xv2 = x_star[(size_t)qc * 5 + 2] * pf[2];
    float xv3 = x_star[(size_t)qc * 5 + 3] * pf[3];
    float xv4 = x_star[(size_t)qc * 5 + 4] * pf[4];
    float pv = pf[5];
    if (tid < 32) red_l[tid] = 0.0f;

    f32x4 acc[2][8];
#pragma unroll
    for (int mi = 0; mi < 2; ++mi)
#pragma unroll
        for (int nj = 0; nj < 8; ++nj) acc[mi][nj] = (f32x4)(0.0f);
    int jmax_w = (56 + ((w + 7) & 7)) * 16 + 15;
    int soff = srow * 256 + ((scc * 16) ^ ((srow & 15) << 4));

    for (int kc = 0; kc < 8; ++kc) {
        int lb = kc * 128 + scc * 8;
        f16x8 hv;
#pragma unroll
        for (int bb = 0; bb < 2; ++bb) {
            float z0[4], z1[4], z2[4], z3[4], z4[4];
            *(float4*)z0 = *(const float4*)&Zst[lb + 4 * bb];
            *(float4*)z1 = *(const float4*)&Zst[M_N + lb + 4 * bb];
            *(float4*)z2 = *(const float4*)&Zst[2 * M_N + lb + 4 * bb];
            *(float4*)z3 = *(const float4*)&Zst[3 * M_N + lb + 4 * bb];
            *(float4*)z4 = *(const float4*)&Zst[4 * M_N + lb + 4 * bb];
#pragma unroll
            for (int e = 0; e < 4; ++e) {
                float dx0 = xv0 - z0[e], dx1 = xv1 - z1[e], dx2 = xv2 - z2[e],
                      dx3 = xv3 - z3[e], dx4 = xv4 - z4[e];
                float d2 = dx0 * dx0 + dx1 * dx1 + dx2 * dx2 + dx3 * dx3 + dx4 * dx4;
                float dd = d2 + 1e-8f;
                float dist = sqrtf(dd);
                float sv = 2.23606798f * dist;
                hv[bb * 4 + e] = (_Float16)(pv * (1.0f + sv + 1.66666667f * dd) * __expf(-sv));
            }
        }
        __syncthreads();
        *(f16x8*)(&kls[soff]) = hv;
        __syncthreads();
        for (int ki = 0; ki < 4; ++ki) {
            int kmin = kc * 128 + ki * 32;
            if (kmin > jmax_w) break;
            f16x8 A_[2];
#pragma unroll
            for (int mi = 0; mi < 2; ++mi) {
                int row = mi * 16 + lrow;
                int cb  = ki * 64 + kgrp * 16;
                A_[mi] = *(const f16x8*)(&kls[row * 256 + (cb ^ ((row & 15) << 4))]);
            }
#pragma unroll
            for (int nj = 0; nj < 8; ++nj) {
                int jng = nj * 8 + ((w + nj) & 7);
                if (kmin > jng * 16 + 15) continue;
                size_t fo = ((size_t)((kc * 4 + ki) * 64 + jng)) * 512 + lane * 8;
                f16x8 Bh = *(const f16x8*)(Wph + fo);
                f16x8 Bl = *(const f16x8*)(Wpl + fo);
#pragma unroll
                for (int mi = 0; mi < 2; ++mi) {
                    acc[mi][nj] = __builtin_amdgcn_mfma_f32_16x16x32_f16(A_[mi], Bh, acc[mi][nj], 0, 0, 0);
                    acc[mi][nj] = __builtin_amdgcn_mfma_f32_16x16x32_f16(A_[mi], Bl, acc[mi][nj], 0, 0, 0);
                }
            }
        }
    }
#pragma unroll
    for (int mi = 0; mi < 2; ++mi) {
#pragma unroll
        for (int q = 0; q < 4; ++q) {
            float s = 0.0f;
#pragma unroll
            for (int nj = 0; nj < 8; ++nj) s = fmaf(acc[mi][nj][q], acc[mi][nj][q], s);
            s += __shfl_xor(s, 1);
            s += __shfl_xor(s, 2);
            s += __shfl_xor(s, 4);
            s += __shfl_xor(s, 8);
            if (lrow == 0) atomicAdd(&red_l[mi * 16 + kgrp * 4 + q], s);
        }
    }
    __syncthreads();
    if (tid < 32) {
        int b = slab * 32 + tid;
        if (b < Bq) out[b] = sqrtf(fmaxf(pv - red_l[tid], 1e-6f));
    }
}

extern "C" void kernel_launch(void* const* d_in, const int* in_sizes, int n_in,
                              void* d_out, int out_size, void* d_ws, size_t ws_size,
                              hipStream_t stream) {
    const float* x_star  = (const float*)d_in[0];
    const float* log_ls  = (const float*)d_in[1];
    const float* log_var = (const float*)d_in[2];
    const float* Z_raw   = (const float*)d_in[3];
    float* out = (float*)d_out;
    int Bq = in_sizes[0] / 5;

    char* ws = (char*)d_ws;
    float*     Kf   = (float*)(ws + OFF_KF);
    float*     Lf   = (float*)(ws + OFF_LF);
    float*     Wf   = (float*)(ws + OFF_WF);
    _Float16*  Wph  = (_Float16*)(ws + OFF_WPH);
    _Float16*  Wpl  = (_Float16*)(ws + OFF_WPL);
    float*     pf   = (float*)(ws + OFF_PF);
    float*     Zst  = (float*)(ws + OFF_ZT);
    float*     redp = (float*)(ws + OFF_RED);
    _Float16*  Ap   = (_Float16*)(ws + OFF_AP);

    int slabs = (Bq + 63) / 64;
    size_t ap_bytes = (size_t)slabs * 128 * 512 * 2;
    bool use_ap = ws_size >= OFF_AP + ap_bytes;

    k_build<<<4096, 256, 0, stream>>>(log_ls, log_var, Z_raw, Kf, pf, Zst);
    if (use_ap)
        k_gen<<<slabs * 32, 256, 0, stream>>>(x_star, pf, Zst, Ap, Bq);

    kw_diag<<<64, 512, 0, stream>>>(Kf, Wf, 0);
    for (int kb = 0; kb < NBK - 1; ++kb) {
        int nt = (NBK - 1 - kb) * 2;
        int grid = nt * (nt + 1) / 2 - 2;
        if (grid < 64) grid = 64;                // tiny-grid stall mitigation
        kw_step<<<grid, 256, 0, stream>>>(Kf, Wf, Lf, kb);
    }
    kw_trtri<<<dim3(4, 7), 512, 0, stream>>>(Lf, Wf);
    kw_pack<<<512, 256, 0, stream>>>(Wf, Wph, Wpl);

    if (use_ap) {
        k_mm<<<dim3(slabs, 2), 512, 0, stream>>>(Ap, Wph, Wpl, redp, Bq);
        k_fin<<<(Bq + 255) / 256, 256, 0, stream>>>(redp, pf, out, Bq);
    } else {
        k_mm_fused<<<(Bq + 31) / 32, 512, 0, stream>>>(x_star, pf, Zst, Wph, Wpl, out, Bq);
    }
}

// Round 10
// 3509.903 us; speedup vs baseline: 1.0484x; 1.0230x over previous
//
#include <hip/hip_runtime.h>
#include <math.h>

// Sizes fixed by the problem.
#define B_TOT 131072
#define M_N   1024
#define BS    128      // Cholesky block size
#define NBK   8        // M_N / BS

typedef float    f32x4 __attribute__((ext_vector_type(4)));
typedef _Float16 f16x8 __attribute__((ext_vector_type(8)));

// Workspace layout (bytes). Total ~17 MB.
enum : size_t {
    OFF_KF  = 0,                          // fp32 K (Schur-updated)  4 MB
    OFF_LF  = (size_t)4 << 20,            // fp32 L off-diag strips  4 MB
    OFF_WF  = (size_t)8 << 20,            // fp32 W = L^-1 (lower)   4 MB
    OFF_WPH = (size_t)12 << 20,           // fp16 W packed hi        2 MB
    OFF_WPL = (size_t)14 << 20,           // fp16 W packed lo        2 MB
    OFF_PF  = (size_t)16 << 20,           // fp32 params (6)
    OFF_ZT  = ((size_t)16 << 20) + 256,   // fp32 Zs_t [5][1024]     20 KB
};

__device__ __constant__ float c_zscale[5] = {0.15f, 0.1f, 0.05f, 800.0f, 20.0f};
__device__ __constant__ float c_zshift[5] = {0.0f, 0.0f, 0.0f, 600.0f, 5.0f};

// ---------------- fused: params + Zst + K = matern52 + jitter (fp32) ----------------
__global__ __launch_bounds__(256) void k_build(const float* __restrict__ log_ls,
                                               const float* __restrict__ log_var,
                                               const float* __restrict__ Zraw,
                                               float* __restrict__ Kf,
                                               float* __restrict__ pf,
                                               float* __restrict__ Zst) {
    __shared__ float ps[6];
    __shared__ float zsi[5];
    int tid = threadIdx.x;
    if (tid < 5) ps[tid] = 1.0f / (__expf(log_ls[tid]) + 1e-8f);
    if (tid == 5) ps[5] = __expf(log_var[0]);
    __syncthreads();
    int i = blockIdx.x >> 2;
    int j = (blockIdx.x & 3) * 256 + tid;
    if (tid < 5) zsi[tid] = (Zraw[i * 5 + tid] * c_zscale[tid] + c_zshift[tid]) * ps[tid];
    __syncthreads();
    float d2 = 0.0f;
#pragma unroll
    for (int d = 0; d < 5; ++d) {
        float zj = (Zraw[j * 5 + d] * c_zscale[d] + c_zshift[d]) * ps[d];
        float df = zsi[d] - zj;
        d2 += df * df;
    }
    float dd = d2 + 1e-8f;
    float dist = sqrtf(dd);
    float s = 2.23606798f * dist;
    float v = ps[5] * (1.0f + s + 1.66666667f * dd) * __expf(-s);
    if (i == j) v += 1e-4f;
    Kf[(size_t)i * M_N + j] = v;
    if (blockIdx.x < 4) {
        int m = blockIdx.x * 256 + tid;
#pragma unroll
        for (int d = 0; d < 5; ++d)
            Zst[d * M_N + m] = (Zraw[m * 5 + d] * c_zscale[d] + c_zshift[d]) * ps[d];
    }
    if (blockIdx.x == 4 && tid < 6) pf[tid] = ps[tid];
}

// ---------------- standalone Cholesky diag block kb=0 (grid padded to 64) -------------
__global__ __launch_bounds__(512) void kw_diag(float* __restrict__ Kf,
                                               float* __restrict__ Wf, int kb) {
    if (blockIdx.x) return;   // grid padding (tiny-grid stall mitigation)
    __shared__ float As[128][129];
    __shared__ float sinv[128];
    int tid = threadIdx.x;
    int r0 = kb * BS;
    for (int idx = tid; idx < BS * BS; idx += 512) {
        int rr = idx >> 7, cc = idx & 127;
        As[rr][cc] = Kf[(size_t)(r0 + rr) * M_N + r0 + cc];
    }
    __syncthreads();

    int r = tid & 127, q = tid >> 7;
    for (int p = 0; p < 16; ++p) {
        int j0 = p * 8;
        for (int j = j0; j < j0 + 8; ++j) {
            if (tid == j) {
                float d = sqrtf(As[j][j]);
                As[j][j] = d;
                sinv[j] = 1.0f / d;
            }
            __syncthreads();
            float arj = 0.0f;
            if (q == 0 && r > j) {
                arj = As[r][j] * sinv[j];
                As[r][j] = arj;
            }
            __syncthreads();
            if (q == 0 && r > j) {
#pragma unroll
                for (int c = j + 1; c < j0 + 8; ++c)
                    As[r][c] -= arj * As[c][j];
            }
        }
        __syncthreads();
        if (p < 15) {
            float a[8];
#pragma unroll
            for (int t = 0; t < 8; ++t) a[t] = As[r][j0 + t];
            for (int c = j0 + 8 + q; c < 128; c += 4) {
                if (r >= c) {
                    float s = As[r][c];
#pragma unroll
                    for (int t = 0; t < 8; ++t) s -= a[t] * As[c][j0 + t];
                    As[r][c] = s;
                }
            }
        }
        __syncthreads();
    }

    if (tid < 128) {
        int c = tid;
        for (int rb = 0; rb < 16; ++rb) {
            int r0b = rb * 8;
            if (c >= r0b + 8) continue;
            float s[8];
#pragma unroll
            for (int i = 0; i < 8; ++i) s[i] = 0.0f;
            for (int t = 0; t < r0b; ++t) {
                if (t >= c) {
                    float xt = (t == c) ? sinv[c] : As[c][t];
#pragma unroll
                    for (int i = 0; i < 8; ++i) s[i] += As[r0b + i][t] * xt;
                }
            }
            float xloc[8];
#pragma unroll
            for (int i = 0; i < 8; ++i) {
                int rr = r0b + i;
                float v = 0.0f;
                if (rr >= c) {
                    v = ((rr == c) ? 1.0f : 0.0f) - s[i];
#pragma unroll
                    for (int t2 = 0; t2 < i; ++t2) {
                        int tt = r0b + t2;
                        if (tt >= c) v -= As[rr][tt] * xloc[t2];
                    }
                    v *= sinv[rr];
                    if (rr > c) As[c][rr] = v;
                }
                xloc[i] = v;
            }
        }
    }
    __syncthreads();
    for (int idx = tid; idx < BS * BS; idx += 512) {
        int rr = idx >> 7, cc = idx & 127;
        if (rr >= cc)
            Wf[(size_t)(r0 + rr) * M_N + r0 + cc] = (rr == cc) ? sinv[rr] : As[cc][rr];
    }
}

// ---------------- strip: S(64x128) = A21[row0..] * W11^T (fp32, into LDS) -------------
static __device__ void d_strip(const float* __restrict__ Kf, const float* __restrict__ Wf,
                               int cb, int row0, float (*S)[129],
                               float (*Ast)[17], float (*Wst)[128], int tid) {
    int c = tid & 127, q = tid >> 7;
    float acc[32];
#pragma unroll
    for (int i = 0; i < 32; ++i) acc[i] = 0.0f;
    for (int tc = 0; tc < 8; ++tc) {
        int tb = tc * 16;
        __syncthreads();
        for (int idx = tid; idx < 64 * 16; idx += 256) {
            int rr = idx >> 4, tt = idx & 15;
            Ast[rr][tt] = Kf[(size_t)(row0 + rr) * M_N + cb + tb + tt];
        }
        for (int idx = tid; idx < 128 * 16; idx += 256) {
            int cc = idx >> 4, tt = idx & 15;
            Wst[tt][cc] = (tb + tt <= cc) ? Wf[(size_t)(cb + cc) * M_N + cb + tb + tt] : 0.0f;
        }
        __syncthreads();
#pragma unroll
        for (int t = 0; t < 16; ++t) {
            float w = Wst[t][c];
#pragma unroll
            for (int i = 0; i < 32; ++i) acc[i] += Ast[q * 32 + i][t] * w;
        }
    }
    __syncthreads();
#pragma unroll
    for (int i = 0; i < 32; ++i) S[q * 32 + i][c] = acc[i];
}

// ---------------- diag factor + inverse, 256 threads (r5-verified) ----------------
static __device__ void d_diag256(float (*As)[129], float* sinv,
                                 float* __restrict__ Wf, int r0, int tid) {
    int r = tid & 127, half = tid >> 7;
    for (int p = 0; p < 16; ++p) {
        int j0 = p * 8;
        for (int j = j0; j < j0 + 8; ++j) {
            if (tid == j) {
                float d = sqrtf(As[j][j]);
                As[j][j] = d;
                sinv[j] = 1.0f / d;
            }
            __syncthreads();
            float arj = 0.0f;
            if (half == 0 && r > j) {
                arj = As[r][j] * sinv[j];
                As[r][j] = arj;
            }
            __syncthreads();
            if (half == 0 && r > j) {
#pragma unroll
                for (int c = j + 1; c < j0 + 8; ++c)
                    As[r][c] -= arj * As[c][j];
            }
        }
        __syncthreads();
        if (p < 15) {
            float a[8];
#pragma unroll
            for (int t = 0; t < 8; ++t) a[t] = As[r][j0 + t];
            for (int c = j0 + 8 + half; c < 128; c += 2) {
                if (r >= c) {
                    float s = As[r][c];
#pragma unroll
                    for (int t = 0; t < 8; ++t) s -= a[t] * As[c][j0 + t];
                    As[r][c] = s;
                }
            }
        }
        __syncthreads();
    }
    if (tid < 128) {
        int c = tid;
        for (int rb = 0; rb < 16; ++rb) {
            int r0b = rb * 8;
            if (c >= r0b + 8) continue;
            float s[8];
#pragma unroll
            for (int i = 0; i < 8; ++i) s[i] = 0.0f;
            for (int t = 0; t < r0b; ++t) {
                if (t >= c) {
                    float xt = (t == c) ? sinv[c] : As[c][t];
#pragma unroll
                    for (int i = 0; i < 8; ++i) s[i] += As[r0b + i][t] * xt;
                }
            }
            float xloc[8];
#pragma unroll
            for (int i = 0; i < 8; ++i) {
                int rr = r0b + i;
                float v = 0.0f;
                if (rr >= c) {
                    v = ((rr == c) ? 1.0f : 0.0f) - s[i];
#pragma unroll
                    for (int t2 = 0; t2 < i; ++t2) {
                        int tt = r0b + t2;
                        if (tt >= c) v -= As[rr][tt] * xloc[t2];
                    }
                    v *= sinv[rr];
                    if (rr > c) As[c][rr] = v;
                }
                xloc[i] = v;
            }
        }
    }
    __syncthreads();
    for (int idx = tid; idx < BS * BS; idx += 256) {
        int rr = idx >> 7, cc = idx & 127;
        if (rr >= cc)
            Wf[(size_t)(r0 + rr) * M_N + r0 + cc] = (rr == cc) ? sinv[rr] : As[cc][rr];
    }
}

// ---------------- step kb: trailing update + NEXT diag fused into block 0 -------------
__global__ __launch_bounds__(256) void kw_step(float* __restrict__ Kf,
                                               float* __restrict__ Wf,
                                               float* __restrict__ Lf, int kb) {
    __shared__ float SA[64][129];
    __shared__ float SB[64][129];
    __shared__ float Ast[64][17];
    __shared__ float Wst[16][128];
    __shared__ float As[128][129];
    __shared__ float sinv[128];
    int tid = threadIdx.x;
    int base = (kb + 1) * BS;
    int cb = kb * BS;
    int tx = tid & 15, ty = tid >> 4;
    int nt = (NBK - 1 - kb) * 2;
    int ntile = nt * (nt + 1) / 2;

    if (blockIdx.x == 0) {
        d_strip(Kf, Wf, cb, base, SA, Ast, Wst, tid);
        d_strip(Kf, Wf, cb, base + 64, SB, Ast, Wst, tid);
        __syncthreads();
#pragma unroll
        for (int qq = 0; qq < 3; ++qq) {
            int qy = (qq == 0) ? 0 : 1;
            int qx = (qq == 2) ? 1 : 0;
            float (*Sy)[129] = qy ? SB : SA;
            float (*Sx)[129] = qx ? SB : SA;
            float acc[4][4];
#pragma unroll
            for (int i = 0; i < 4; ++i)
#pragma unroll
                for (int j = 0; j < 4; ++j) acc[i][j] = 0.0f;
            for (int t = 0; t < 128; ++t) {
                float a[4], b[4];
#pragma unroll
                for (int i = 0; i < 4; ++i) a[i] = Sy[ty * 4 + i][t];
#pragma unroll
                for (int j = 0; j < 4; ++j) b[j] = Sx[tx * 4 + j][t];
#pragma unroll
                for (int i = 0; i < 4; ++i)
#pragma unroll
                    for (int j = 0; j < 4; ++j) acc[i][j] = fmaf(a[i], b[j], acc[i][j]);
            }
#pragma unroll
            for (int i = 0; i < 4; ++i)
#pragma unroll
                for (int j = 0; j < 4; ++j)
                    As[qy * 64 + ty * 4 + i][qx * 64 + tx * 4 + j] =
                        Kf[(size_t)(base + qy * 64 + ty * 4 + i) * M_N +
                           base + qx * 64 + tx * 4 + j] - acc[i][j];
        }
        for (int idx = tid; idx < 64 * 128; idx += 256) {
            int rr = idx >> 7, cc = idx & 127;
            Lf[(size_t)(base + rr) * M_N + cb + cc]      = SA[rr][cc];
            Lf[(size_t)(base + 64 + rr) * M_N + cb + cc] = SB[rr][cc];
        }
        __syncthreads();
        d_diag256(As, sinv, Wf, base, tid);
    } else {
        int vp = blockIdx.x + 2;
        if (vp >= ntile) return;   // grid padding
        int by = 0;
        while ((by + 1) * (by + 2) / 2 <= vp) ++by;
        int bx = vp - by * (by + 1) / 2;
        int gr0 = base + by * 64, gc0 = base + bx * 64;
        d_strip(Kf, Wf, cb, gr0, SA, Ast, Wst, tid);
        if (bx != by) d_strip(Kf, Wf, cb, gc0, SB, Ast, Wst, tid);
        float (*PB)[129] = (bx == by) ? SA : SB;
        __syncthreads();
        float acc[4][4];
#pragma unroll
        for (int i = 0; i < 4; ++i)
#pragma unroll
            for (int j = 0; j < 4; ++j) acc[i][j] = 0.0f;
        for (int t = 0; t < 128; ++t) {
            float a[4], b[4];
#pragma unroll
            for (int i = 0; i < 4; ++i) a[i] = SA[ty * 4 + i][t];
#pragma unroll
            for (int j = 0; j < 4; ++j) b[j] = PB[tx * 4 + j][t];
#pragma unroll
            for (int i = 0; i < 4; ++i)
#pragma unroll
                for (int j = 0; j < 4; ++j) acc[i][j] = fmaf(a[i], b[j], acc[i][j]);
        }
#pragma unroll
        for (int i = 0; i < 4; ++i)
#pragma unroll
            for (int j = 0; j < 4; ++j)
                Kf[(size_t)(gr0 + ty * 4 + i) * M_N + gc0 + tx * 4 + j] -= acc[i][j];
        if (by == bx) {
            for (int idx = tid; idx < 64 * 128; idx += 256)
                Lf[(size_t)(gr0 + (idx >> 7)) * M_N + cb + (idx & 127)] =
                    SA[idx >> 7][idx & 127];
        }
    }
}

// ---------------- trtri: single launch, fp32 (verified r7) ----------------
__global__ __launch_bounds__(512) void kw_trtri(const float* __restrict__ Lf,
                                                float* __restrict__ Wf) {
    __shared__ float Ls[128][33];
    __shared__ float Ws[32][33];
    __shared__ float Whist[6][128][33];
    __shared__ float Ps[128][33];
    int j  = blockIdx.y;
    int ct = blockIdx.x;
    int c0 = j * BS + ct * 32;
    int tid = threadIdx.x;
    int rq = tid >> 2, cq = tid & 3;

    for (int i = j + 1; i < 8; ++i) {
        float acc[8];
#pragma unroll
        for (int c = 0; c < 8; ++c) acc[c] = 0.0f;
        for (int t = j; t < i; ++t) {
            for (int ch = 0; ch < 4; ++ch) {
                int tb = t * BS + ch * 32;
                __syncthreads();
                for (int idx = tid; idx < 128 * 32; idx += 512) {
                    int rr = idx >> 5, tt = idx & 31;
                    Ls[rr][tt] = Lf[(size_t)(i * BS + rr) * M_N + tb + tt];
                }
                if (t == j) {
                    for (int idx = tid; idx < 32 * 32; idx += 512) {
                        int tt = idx >> 5, cc = idx & 31;
                        int gr = tb + tt, gc = c0 + cc;
                        Ws[tt][cc] = (gr >= gc) ? Wf[(size_t)gr * M_N + gc] : 0.0f;
                    }
                }
                __syncthreads();
                if (t == j) {
#pragma unroll
                    for (int tt = 0; tt < 32; ++tt) {
                        float l = Ls[rq][tt];
#pragma unroll
                        for (int c = 0; c < 8; ++c)
                            acc[c] = fmaf(l, Ws[tt][cq * 8 + c], acc[c]);
                    }
                } else {
                    const float (*Wh)[33] = Whist[t - j - 1];
#pragma unroll
                    for (int tt = 0; tt < 32; ++tt) {
                        float l = Ls[rq][tt];
#pragma unroll
                        for (int c = 0; c < 8; ++c)
                            acc[c] = fmaf(l, Wh[ch * 32 + tt][cq * 8 + c], acc[c]);
                    }
                }
            }
        }
        __syncthreads();
#pragma unroll
        for (int c = 0; c < 8; ++c) Ps[rq][cq * 8 + c] = acc[c];
        float a2[8];
#pragma unroll
        for (int c = 0; c < 8; ++c) a2[c] = 0.0f;
        for (int ch = 0; ch < 4; ++ch) {
            __syncthreads();
            for (int idx = tid; idx < 128 * 32; idx += 512) {
                int rr = idx >> 5, tt = idx & 31;
                Ls[rr][tt] = (rr >= ch * 32 + tt)
                           ? Wf[(size_t)(i * BS + rr) * M_N + i * BS + ch * 32 + tt] : 0.0f;
            }
            __syncthreads();
#pragma unroll
            for (int tt = 0; tt < 32; ++tt) {
                float l = Ls[rq][tt];
#pragma unroll
                for (int c = 0; c < 8; ++c)
                    a2[c] = fmaf(l, Ps[ch * 32 + tt][cq * 8 + c], a2[c]);
            }
        }
        __syncthreads();
#pragma unroll
        for (int c = 0; c < 8; ++c) {
            float v = -a2[c];
            Wf[(size_t)(i * BS + rq) * M_N + c0 + cq * 8 + c] = v;
            if (i < 7) Whist[i - j - 1][rq][cq * 8 + c] = v;
        }
        __syncthreads();
    }
}

// ---------------- pack W (fp32) into MFMA B-fragment order, fp16 hi/lo ----------------
__global__ void kw_pack(const float* __restrict__ Wf, _Float16* __restrict__ Wph,
                        _Float16* __restrict__ Wpl) {
    int T = blockIdx.x * 256 + threadIdx.x;
    int lane = T & 63, fid = T >> 6;
    int jn = fid & 63, kik = fid >> 6;
    int ki = kik & 3, kc = kik >> 2;
    int j  = jn * 16 + (lane & 15);
    int kb = kc * 128 + ki * 32 + (lane >> 4) * 8;
    f16x8 h, lo;
#pragma unroll
    for (int e = 0; e < 8; ++e) {
        int k = kb + e;
        float v = (k <= j) ? Wf[(size_t)j * M_N + k] : 0.0f;
        _Float16 hh = (_Float16)v;
        h[e]  = hh;
        lo[e] = (_Float16)(v - (float)hh);
    }
    size_t off = (size_t)fid * 512 + lane * 8;
    *(f16x8*)(Wph + off) = h;
    *(f16x8*)(Wpl + off) = lo;
}

// ---------------- main fused MFMA kernel: 64 rows x 1024 cols, 2 col-passes ----------
// acc[4][4] only (64 f32) -- columns split into two passes, k-tile re-staged per pass.
__global__ __launch_bounds__(512, 2) void k_mm(const float* __restrict__ x_star,
                                               const float* __restrict__ pf,
                                               const float* __restrict__ Zst,
                                               const _Float16* __restrict__ Wph,
                                               const _Float16* __restrict__ Wpl,
                                               float* __restrict__ out, int Bq) {
    __shared__ __align__(16) char kls[64 * 256];  // fp16 k-tile, r8-verified 0-conflict swz
    __shared__ float red_l[64];
    int tid  = threadIdx.x;
    int slab = blockIdx.x;
    int w = tid >> 6, lane = tid & 63;
    int lrow = lane & 15, kgrp = lane >> 4;

    // staging identity: rows {srow0, srow0+32}, col-group scc (8 cols, 16B)
    int scc = tid & 15, srow0 = tid >> 4;
    int q0 = slab * 64 + srow0;
    int q1 = q0 + 32;
    int qa = (q0 < Bq) ? q0 : (Bq - 1);
    int qb = (q1 < Bq) ? q1 : (Bq - 1);
    float xa0 = x_star[(size_t)qa * 5 + 0] * pf[0];
    float xa1 = x_star[(size_t)qa * 5 + 1] * pf[1];
    float xa2 = x_star[(size_t)qa * 5 + 2] * pf[2];
    float xa3 = x_star[(size_t)qa * 5 + 3] * pf[3];
    float xa4 = x_star[(size_t)qa * 5 + 4] * pf[4];
    float xb0 = x_star[(size_t)qb * 5 + 0] * pf[0];
    float xb1 = x_star[(size_t)qb * 5 + 1] * pf[1];
    float xb2 = x_star[(size_t)qb * 5 + 2] * pf[2];
    float xb3 = x_star[(size_t)qb * 5 + 3] * pf[3];
    float xb4 = x_star[(size_t)qb * 5 + 4] * pf[4];
    float pv = pf[5];
    if (tid < 64) red_l[tid] = 0.0f;

    int swz = (scc * 16) ^ ((srow0 & 15) << 4);
    int soff0 = srow0 * 256 + swz;
    int soff1 = (srow0 + 32) * 256 + swz;

    for (int pp = 0; pp < 2; ++pp) {
        f32x4 acc[4][4];
#pragma unroll
        for (int mi = 0; mi < 4; ++mi)
#pragma unroll
            for (int nj = 0; nj < 4; ++nj) acc[mi][nj] = (f32x4)(0.0f);

        int jmax_w = (pp * 32 + 24 + ((w + 3) & 7)) * 16 + 15;  // jng = pp*32+8nj+((w+nj)&7)
        int KC = pp ? 8 : 4;            // pass 0 cols < 512 need only kc 0..3

        for (int kc = 0; kc < KC; ++kc) {
            // ---- compute this thread's 16 k values into regs (fp16) ----
            f16x8 h0, h1;
#pragma unroll
            for (int bb = 0; bb < 2; ++bb) {
                int lb = kc * 128 + scc * 8 + bb * 4;
                float z0[4], z1[4], z2[4], z3[4], z4[4];
                *(float4*)z0 = *(const float4*)&Zst[lb];
                *(float4*)z1 = *(const float4*)&Zst[M_N + lb];
                *(float4*)z2 = *(const float4*)&Zst[2 * M_N + lb];
                *(float4*)z3 = *(const float4*)&Zst[3 * M_N + lb];
                *(float4*)z4 = *(const float4*)&Zst[4 * M_N + lb];
#pragma unroll
                for (int e = 0; e < 4; ++e) {
                    float dx0 = xa0 - z0[e], dx1 = xa1 - z1[e], dx2 = xa2 - z2[e],
                          dx3 = xa3 - z3[e], dx4 = xa4 - z4[e];
                    float d2 = dx0 * dx0 + dx1 * dx1 + dx2 * dx2 + dx3 * dx3 + dx4 * dx4;
                    float dd = d2 + 1e-8f;
                    float dist = sqrtf(dd);
                    float sv = 2.23606798f * dist;
                    h0[bb * 4 + e] = (_Float16)(pv * (1.0f + sv + 1.66666667f * dd) * __expf(-sv));
                    float ex0 = xb0 - z0[e], ex1 = xb1 - z1[e], ex2 = xb2 - z2[e],
                          ex3 = xb3 - z3[e], ex4 = xb4 - z4[e];
                    float e2 = ex0 * ex0 + ex1 * ex1 + ex2 * ex2 + ex3 * ex3 + ex4 * ex4;
                    float ee = e2 + 1e-8f;
                    float edist = sqrtf(ee);
                    float esv = 2.23606798f * edist;
                    h1[bb * 4 + e] = (_Float16)(pv * (1.0f + esv + 1.66666667f * ee) * __expf(-esv));
                }
            }
            __syncthreads();                  // prior-chunk MFMA reads done
            *(f16x8*)(&kls[soff0]) = h0;
            *(f16x8*)(&kls[soff1]) = h1;
            __syncthreads();                  // chunk visible

            // ---- MFMA over this K chunk, this pass's 32 col-fragments ----
            for (int ki = 0; ki < 4; ++ki) {
                int kmin = kc * 128 + ki * 32;
                if (kmin > jmax_w) break;            // wave-uniform
                f16x8 A_[4];
#pragma unroll
                for (int mi = 0; mi < 4; ++mi) {
                    int row = mi * 16 + lrow;
                    int cb  = ki * 64 + kgrp * 16;
                    A_[mi] = *(const f16x8*)(&kls[row * 256 + (cb ^ ((row & 15) << 4))]);
                }
#pragma unroll
                for (int nj = 0; nj < 4; ++nj) {
                    int jng = pp * 32 + nj * 8 + ((w + nj) & 7);  // balanced interleave
                    if (kmin > jng * 16 + 15) continue;           // all-zero W fragment
                    size_t fo = ((size_t)((kc * 4 + ki) * 64 + jng)) * 512 + lane * 8;
                    f16x8 Bh = *(const f16x8*)(Wph + fo);
                    f16x8 Bl = *(const f16x8*)(Wpl + fo);
#pragma unroll
                    for (int mi = 0; mi < 4; ++mi) {
                        acc[mi][nj] = __builtin_amdgcn_mfma_f32_16x16x32_f16(A_[mi], Bh, acc[mi][nj], 0, 0, 0);
                        acc[mi][nj] = __builtin_amdgcn_mfma_f32_16x16x32_f16(A_[mi], Bl, acc[mi][nj], 0, 0, 0);
                    }
                }
            }
        }

        // per-pass epilogue: red[row] += y^2 over this pass's columns
#pragma unroll
        for (int mi = 0; mi < 4; ++mi) {
#pragma unroll
            for (int q = 0; q < 4; ++q) {
                float s = 0.0f;
#pragma unroll
                for (int nj = 0; nj < 4; ++nj) s = fmaf(acc[mi][nj][q], acc[mi][nj][q], s);
                s += __shfl_xor(s, 1);
                s += __shfl_xor(s, 2);
                s += __shfl_xor(s, 4);
                s += __shfl_xor(s, 8);
                if (lrow == 0) atomicAdd(&red_l[mi * 16 + kgrp * 4 + q], s);
            }
        }
        __syncthreads();   // pass reads of kls done; red_l atomics visible next pass
    }

    if (tid < 64) {
        int b = slab * 64 + tid;
        if (b < Bq) out[b] = sqrtf(fmaxf(pv - red_l[tid], 1e-6f));
    }
}

extern "C" void kernel_launch(void* const* d_in, const int* in_sizes, int n_in,
                              void* d_out, int out_size, void* d_ws, size_t ws_size,
                              hipStream_t stream) {
    const float* x_star  = (const float*)d_in[0];
    const float* log_ls  = (const float*)d_in[1];
    const float* log_var = (const float*)d_in[2];
    const float* Z_raw   = (const float*)d_in[3];
    float* out = (float*)d_out;
    int Bq = in_sizes[0] / 5;

    char* ws = (char*)d_ws;
    float*     Kf  = (float*)(ws + OFF_KF);
    float*     Lf  = (float*)(ws + OFF_LF);
    float*     Wf  = (float*)(ws + OFF_WF);
    _Float16*  Wph = (_Float16*)(ws + OFF_WPH);
    _Float16*  Wpl = (_Float16*)(ws + OFF_WPL);
    float*     pf  = (float*)(ws + OFF_PF);
    float*     Zst = (float*)(ws + OFF_ZT);

    k_build<<<4096, 256, 0, stream>>>(log_ls, log_var, Z_raw, Kf, pf, Zst);
    kw_diag<<<64, 512, 0, stream>>>(Kf, Wf, 0);
    for (int kb = 0; kb < NBK - 1; ++kb) {
        int nt = (NBK - 1 - kb) * 2;
        int grid = nt * (nt + 1) / 2 - 2;
        if (grid < 64) grid = 64;                // tiny-grid stall mitigation
        kw_step<<<grid, 256, 0, stream>>>(Kf, Wf, Lf, kb);
    }
    kw_trtri<<<dim3(4, 7), 512, 0, stream>>>(Lf, Wf);
    kw_pack<<<512, 256, 0, stream>>>(Wf, Wph, Wpl);

    int slabs = (Bq + 63) / 64;
    k_mm<<<slabs, 512, 0, stream>>>(x_star, pf, Zst, Wph, Wpl, out, Bq);
}

// Round 12
// 3476.789 us; speedup vs baseline: 1.0584x; 1.0095x over previous
//
#include <hip/hip_runtime.h>
#include <math.h>

// Sizes fixed by the problem.
#define B_TOT 131072
#define M_N   1024
#define BS    128      // Cholesky block size
#define NBK   8        // M_N / BS

typedef float    f32x4 __attribute__((ext_vector_type(4)));
typedef _Float16 f16x8 __attribute__((ext_vector_type(8)));

// Workspace layout (bytes). Total ~17 MB.
enum : size_t {
    OFF_KF  = 0,                          // fp32 K (Schur-updated)  4 MB
    OFF_LF  = (size_t)4 << 20,            // fp32 L off-diag strips  4 MB
    OFF_WF  = (size_t)8 << 20,            // fp32 W = L^-1 (lower)   4 MB
    OFF_WPH = (size_t)12 << 20,           // fp16 W packed hi        2 MB
    OFF_WPL = (size_t)14 << 20,           // fp16 W packed lo        2 MB
    OFF_PF  = (size_t)16 << 20,           // fp32 params (6)
    OFF_ZT  = ((size_t)16 << 20) + 256,   // fp32 Zs_t [5][1024]     20 KB
};

__device__ __constant__ float c_zscale[5] = {0.15f, 0.1f, 0.05f, 800.0f, 20.0f};
__device__ __constant__ float c_zshift[5] = {0.0f, 0.0f, 0.0f, 600.0f, 5.0f};

// ---------------- fused: params + Zst + K = matern52 + jitter (fp32) ----------------
__global__ __launch_bounds__(256) void k_build(const float* __restrict__ log_ls,
                                               const float* __restrict__ log_var,
                                               const float* __restrict__ Zraw,
                                               float* __restrict__ Kf,
                                               float* __restrict__ pf,
                                               float* __restrict__ Zst) {
    __shared__ float ps[6];
    __shared__ float zsi[5];
    int tid = threadIdx.x;
    if (tid < 5) ps[tid] = 1.0f / (__expf(log_ls[tid]) + 1e-8f);
    if (tid == 5) ps[5] = __expf(log_var[0]);
    __syncthreads();
    int i = blockIdx.x >> 2;
    int j = (blockIdx.x & 3) * 256 + tid;
    if (tid < 5) zsi[tid] = (Zraw[i * 5 + tid] * c_zscale[tid] + c_zshift[tid]) * ps[tid];
    __syncthreads();
    float d2 = 0.0f;
#pragma unroll
    for (int d = 0; d < 5; ++d) {
        float zj = (Zraw[j * 5 + d] * c_zscale[d] + c_zshift[d]) * ps[d];
        float df = zsi[d] - zj;
        d2 += df * df;
    }
    float dd = d2 + 1e-8f;
    float dist = sqrtf(dd);
    float s = 2.23606798f * dist;
    float v = ps[5] * (1.0f + s + 1.66666667f * dd) * __expf(-s);
    if (i == j) v += 1e-4f;
    Kf[(size_t)i * M_N + j] = v;
    if (blockIdx.x < 4) {
        int m = blockIdx.x * 256 + tid;
#pragma unroll
        for (int d = 0; d < 5; ++d)
            Zst[d * M_N + m] = (Zraw[m * 5 + d] * c_zscale[d] + c_zshift[d]) * ps[d];
    }
    if (blockIdx.x == 4 && tid < 6) pf[tid] = ps[tid];
}

// ---------------- standalone Cholesky diag block kb=0 (grid padded to 64) -------------
__global__ __launch_bounds__(512) void kw_diag(float* __restrict__ Kf,
                                               float* __restrict__ Wf, int kb) {
    if (blockIdx.x) return;   // grid padding (tiny-grid stall mitigation)
    __shared__ float As[128][129];
    __shared__ float sinv[128];
    int tid = threadIdx.x;
    int r0 = kb * BS;
    for (int idx = tid; idx < BS * BS; idx += 512) {
        int rr = idx >> 7, cc = idx & 127;
        As[rr][cc] = Kf[(size_t)(r0 + rr) * M_N + r0 + cc];
    }
    __syncthreads();

    int r = tid & 127, q = tid >> 7;
    for (int p = 0; p < 16; ++p) {
        int j0 = p * 8;
        for (int j = j0; j < j0 + 8; ++j) {
            if (tid == j) {
                float d = sqrtf(As[j][j]);
                As[j][j] = d;
                sinv[j] = 1.0f / d;
            }
            __syncthreads();
            float arj = 0.0f;
            if (q == 0 && r > j) {
                arj = As[r][j] * sinv[j];
                As[r][j] = arj;
            }
            __syncthreads();
            if (q == 0 && r > j) {
#pragma unroll
                for (int c = j + 1; c < j0 + 8; ++c)
                    As[r][c] -= arj * As[c][j];
            }
        }
        __syncthreads();
        if (p < 15) {
            float a[8];
#pragma unroll
            for (int t = 0; t < 8; ++t) a[t] = As[r][j0 + t];
            for (int c = j0 + 8 + q; c < 128; c += 4) {
                if (r >= c) {
                    float s = As[r][c];
#pragma unroll
                    for (int t = 0; t < 8; ++t) s -= a[t] * As[c][j0 + t];
                    As[r][c] = s;
                }
            }
        }
        __syncthreads();
    }

    if (tid < 128) {
        int c = tid;
        for (int rb = 0; rb < 16; ++rb) {
            int r0b = rb * 8;
            if (c >= r0b + 8) continue;
            float s[8];
#pragma unroll
            for (int i = 0; i < 8; ++i) s[i] = 0.0f;
            for (int t = 0; t < r0b; ++t) {
                if (t >= c) {
                    float xt = (t == c) ? sinv[c] : As[c][t];
#pragma unroll
                    for (int i = 0; i < 8; ++i) s[i] += As[r0b + i][t] * xt;
                }
            }
            float xloc[8];
#pragma unroll
            for (int i = 0; i < 8; ++i) {
                int rr = r0b + i;
                float v = 0.0f;
                if (rr >= c) {
                    v = ((rr == c) ? 1.0f : 0.0f) - s[i];
#pragma unroll
                    for (int t2 = 0; t2 < i; ++t2) {
                        int tt = r0b + t2;
                        if (tt >= c) v -= As[rr][tt] * xloc[t2];
                    }
                    v *= sinv[rr];
                    if (rr > c) As[c][rr] = v;
                }
                xloc[i] = v;
            }
        }
    }
    __syncthreads();
    for (int idx = tid; idx < BS * BS; idx += 512) {
        int rr = idx >> 7, cc = idx & 127;
        if (rr >= cc)
            Wf[(size_t)(r0 + rr) * M_N + r0 + cc] = (rr == cc) ? sinv[rr] : As[cc][rr];
    }
}

// ---------------- strip: S(64x128) = A21[row0..] * W11^T (fp32, into LDS) -------------
static __device__ void d_strip(const float* __restrict__ Kf, const float* __restrict__ Wf,
                               int cb, int row0, float (*S)[129],
                               float (*Ast)[17], float (*Wst)[128], int tid) {
    int c = tid & 127, q = tid >> 7;
    float acc[32];
#pragma unroll
    for (int i = 0; i < 32; ++i) acc[i] = 0.0f;
    for (int tc = 0; tc < 8; ++tc) {
        int tb = tc * 16;
        __syncthreads();
        for (int idx = tid; idx < 64 * 16; idx += 256) {
            int rr = idx >> 4, tt = idx & 15;
            Ast[rr][tt] = Kf[(size_t)(row0 + rr) * M_N + cb + tb + tt];
        }
        for (int idx = tid; idx < 128 * 16; idx += 256) {
            int cc = idx >> 4, tt = idx & 15;
            Wst[tt][cc] = (tb + tt <= cc) ? Wf[(size_t)(cb + cc) * M_N + cb + tb + tt] : 0.0f;
        }
        __syncthreads();
#pragma unroll
        for (int t = 0; t < 16; ++t) {
            float w = Wst[t][c];
#pragma unroll
            for (int i = 0; i < 32; ++i) acc[i] += Ast[q * 32 + i][t] * w;
        }
    }
    __syncthreads();
#pragma unroll
    for (int i = 0; i < 32; ++i) S[q * 32 + i][c] = acc[i];
}

// ---------------- diag factor + inverse, 256 threads (r5-verified) ----------------
static __device__ void d_diag256(float (*As)[129], float* sinv,
                                 float* __restrict__ Wf, int r0, int tid) {
    int r = tid & 127, half = tid >> 7;
    for (int p = 0; p < 16; ++p) {
        int j0 = p * 8;
        for (int j = j0; j < j0 + 8; ++j) {
            if (tid == j) {
                float d = sqrtf(As[j][j]);
                As[j][j] = d;
                sinv[j] = 1.0f / d;
            }
            __syncthreads();
            float arj = 0.0f;
            if (half == 0 && r > j) {
                arj = As[r][j] * sinv[j];
                As[r][j] = arj;
            }
            __syncthreads();
            if (half == 0 && r > j) {
#pragma unroll
                for (int c = j + 1; c < j0 + 8; ++c)
                    As[r][c] -= arj * As[c][j];
            }
        }
        __syncthreads();
        if (p < 15) {
            float a[8];
#pragma unroll
            for (int t = 0; t < 8; ++t) a[t] = As[r][j0 + t];
            for (int c = j0 + 8 + half; c < 128; c += 2) {
                if (r >= c) {
                    float s = As[r][c];
#pragma unroll
                    for (int t = 0; t < 8; ++t) s -= a[t] * As[c][j0 + t];
                    As[r][c] = s;
                }
            }
        }
        __syncthreads();
    }
    if (tid < 128) {
        int c = tid;
        for (int rb = 0; rb < 16; ++rb) {
            int r0b = rb * 8;
            if (c >= r0b + 8) continue;
            float s[8];
#pragma unroll
            for (int i = 0; i < 8; ++i) s[i] = 0.0f;
            for (int t = 0; t < r0b; ++t) {
                if (t >= c) {
                    float xt = (t == c) ? sinv[c] : As[c][t];
#pragma unroll
                    for (int i = 0; i < 8; ++i) s[i] += As[r0b + i][t] * xt;
                }
            }
            float xloc[8];
#pragma unroll
            for (int i = 0; i < 8; ++i) {
                int rr = r0b + i;
                float v = 0.0f;
                if (rr >= c) {
                    v = ((rr == c) ? 1.0f : 0.0f) - s[i];
#pragma unroll
                    for (int t2 = 0; t2 < i; ++t2) {
                        int tt = r0b + t2;
                        if (tt >= c) v -= As[rr][tt] * xloc[t2];
                    }
                    v *= sinv[rr];
                    if (rr > c) As[c][rr] = v;
                }
                xloc[i] = v;
            }
        }
    }
    __syncthreads();
    for (int idx = tid; idx < BS * BS; idx += 256) {
        int rr = idx >> 7, cc = idx & 127;
        if (rr >= cc)
            Wf[(size_t)(r0 + rr) * M_N + r0 + cc] = (rr == cc) ? sinv[rr] : As[cc][rr];
    }
}

// ---------------- step kb: trailing update + NEXT diag fused into block 0 -------------
__global__ __launch_bounds__(256) void kw_step(float* __restrict__ Kf,
                                               float* __restrict__ Wf,
                                               float* __restrict__ Lf, int kb) {
    __shared__ float SA[64][129];
    __shared__ float SB[64][129];
    __shared__ float Ast[64][17];
    __shared__ float Wst[16][128];
    __shared__ float As[128][129];
    __shared__ float sinv[128];
    int tid = threadIdx.x;
    int base = (kb + 1) * BS;
    int cb = kb * BS;
    int tx = tid & 15, ty = tid >> 4;
    int nt = (NBK - 1 - kb) * 2;
    int ntile = nt * (nt + 1) / 2;

    if (blockIdx.x == 0) {
        d_strip(Kf, Wf, cb, base, SA, Ast, Wst, tid);
        d_strip(Kf, Wf, cb, base + 64, SB, Ast, Wst, tid);
        __syncthreads();
#pragma unroll
        for (int qq = 0; qq < 3; ++qq) {
            int qy = (qq == 0) ? 0 : 1;
            int qx = (qq == 2) ? 1 : 0;
            float (*Sy)[129] = qy ? SB : SA;
            float (*Sx)[129] = qx ? SB : SA;
            float acc[4][4];
#pragma unroll
            for (int i = 0; i < 4; ++i)
#pragma unroll
                for (int j = 0; j < 4; ++j) acc[i][j] = 0.0f;
            for (int t = 0; t < 128; ++t) {
                float a[4], b[4];
#pragma unroll
                for (int i = 0; i < 4; ++i) a[i] = Sy[ty * 4 + i][t];
#pragma unroll
                for (int j = 0; j < 4; ++j) b[j] = Sx[tx * 4 + j][t];
#pragma unroll
                for (int i = 0; i < 4; ++i)
#pragma unroll
                    for (int j = 0; j < 4; ++j) acc[i][j] = fmaf(a[i], b[j], acc[i][j]);
            }
#pragma unroll
            for (int i = 0; i < 4; ++i)
#pragma unroll
                for (int j = 0; j < 4; ++j)
                    As[qy * 64 + ty * 4 + i][qx * 64 + tx * 4 + j] =
                        Kf[(size_t)(base + qy * 64 + ty * 4 + i) * M_N +
                           base + qx * 64 + tx * 4 + j] - acc[i][j];
        }
        for (int idx = tid; idx < 64 * 128; idx += 256) {
            int rr = idx >> 7, cc = idx & 127;
            Lf[(size_t)(base + rr) * M_N + cb + cc]      = SA[rr][cc];
            Lf[(size_t)(base + 64 + rr) * M_N + cb + cc] = SB[rr][cc];
        }
        __syncthreads();
        d_diag256(As, sinv, Wf, base, tid);
    } else {
        int vp = blockIdx.x + 2;
        if (vp >= ntile) return;   // grid padding
        int by = 0;
        while ((by + 1) * (by + 2) / 2 <= vp) ++by;
        int bx = vp - by * (by + 1) / 2;
        int gr0 = base + by * 64, gc0 = base + bx * 64;
        d_strip(Kf, Wf, cb, gr0, SA, Ast, Wst, tid);
        if (bx != by) d_strip(Kf, Wf, cb, gc0, SB, Ast, Wst, tid);
        float (*PB)[129] = (bx == by) ? SA : SB;
        __syncthreads();
        float acc[4][4];
#pragma unroll
        for (int i = 0; i < 4; ++i)
#pragma unroll
            for (int j = 0; j < 4; ++j) acc[i][j] = 0.0f;
        for (int t = 0; t < 128; ++t) {
            float a[4], b[4];
#pragma unroll
            for (int i = 0; i < 4; ++i) a[i] = SA[ty * 4 + i][t];
#pragma unroll
            for (int j = 0; j < 4; ++j) b[j] = PB[tx * 4 + j][t];
#pragma unroll
            for (int i = 0; i < 4; ++i)
#pragma unroll
                for (int j = 0; j < 4; ++j) acc[i][j] = fmaf(a[i], b[j], acc[i][j]);
        }
#pragma unroll
        for (int i = 0; i < 4; ++i)
#pragma unroll
            for (int j = 0; j < 4; ++j)
                Kf[(size_t)(gr0 + ty * 4 + i) * M_N + gc0 + tx * 4 + j] -= acc[i][j];
        if (by == bx) {
            for (int idx = tid; idx < 64 * 128; idx += 256)
                Lf[(size_t)(gr0 + (idx >> 7)) * M_N + cb + (idx & 127)] =
                    SA[idx >> 7][idx & 127];
        }
    }
}

// ---------------- trtri: single launch, fp32 (verified r7) ----------------
__global__ __launch_bounds__(512) void kw_trtri(const float* __restrict__ Lf,
                                                float* __restrict__ Wf) {
    __shared__ float Ls[128][33];
    __shared__ float Ws[32][33];
    __shared__ float Whist[6][128][33];
    __shared__ float Ps[128][33];
    int j  = blockIdx.y;
    int ct = blockIdx.x;
    int c0 = j * BS + ct * 32;
    int tid = threadIdx.x;
    int rq = tid >> 2, cq = tid & 3;

    for (int i = j + 1; i < 8; ++i) {
        float acc[8];
#pragma unroll
        for (int c = 0; c < 8; ++c) acc[c] = 0.0f;
        for (int t = j; t < i; ++t) {
            for (int ch = 0; ch < 4; ++ch) {
                int tb = t * BS + ch * 32;
                __syncthreads();
                for (int idx = tid; idx < 128 * 32; idx += 512) {
                    int rr = idx >> 5, tt = idx & 31;
                    Ls[rr][tt] = Lf[(size_t)(i * BS + rr) * M_N + tb + tt];
                }
                if (t == j) {
                    for (int idx = tid; idx < 32 * 32; idx += 512) {
                        int tt = idx >> 5, cc = idx & 31;
                        int gr = tb + tt, gc = c0 + cc;
                        Ws[tt][cc] = (gr >= gc) ? Wf[(size_t)gr * M_N + gc] : 0.0f;
                    }
                }
                __syncthreads();
                if (t == j) {
#pragma unroll
                    for (int tt = 0; tt < 32; ++tt) {
                        float l = Ls[rq][tt];
#pragma unroll
                        for (int c = 0; c < 8; ++c)
                            acc[c] = fmaf(l, Ws[tt][cq * 8 + c], acc[c]);
                    }
                } else {
                    const float (*Wh)[33] = Whist[t - j - 1];
#pragma unroll
                    for (int tt = 0; tt < 32; ++tt) {
                        float l = Ls[rq][tt];
#pragma unroll
                        for (int c = 0; c < 8; ++c)
                            acc[c] = fmaf(l, Wh[ch * 32 + tt][cq * 8 + c], acc[c]);
                    }
                }
            }
        }
        __syncthreads();
#pragma unroll
        for (int c = 0; c < 8; ++c) Ps[rq][cq * 8 + c] = acc[c];
        float a2[8];
#pragma unroll
        for (int c = 0; c < 8; ++c) a2[c] = 0.0f;
        for (int ch = 0; ch < 4; ++ch) {
            __syncthreads();
            for (int idx = tid; idx < 128 * 32; idx += 512) {
                int rr = idx >> 5, tt = idx & 31;
                Ls[rr][tt] = (rr >= ch * 32 + tt)
                           ? Wf[(size_t)(i * BS + rr) * M_N + i * BS + ch * 32 + tt] : 0.0f;
            }
            __syncthreads();
#pragma unroll
            for (int tt = 0; tt < 32; ++tt) {
                float l = Ls[rq][tt];
#pragma unroll
                for (int c = 0; c < 8; ++c)
                    a2[c] = fmaf(l, Ps[ch * 32 + tt][cq * 8 + c], a2[c]);
            }
        }
        __syncthreads();
#pragma unroll
        for (int c = 0; c < 8; ++c) {
            float v = -a2[c];
            Wf[(size_t)(i * BS + rq) * M_N + c0 + cq * 8 + c] = v;
            if (i < 7) Whist[i - j - 1][rq][cq * 8 + c] = v;
        }
        __syncthreads();
    }
}

// ---------------- pack W (fp32) into MFMA B-fragment order, fp16 hi/lo ----------------
__global__ void kw_pack(const float* __restrict__ Wf, _Float16* __restrict__ Wph,
                        _Float16* __restrict__ Wpl) {
    int T = blockIdx.x * 256 + threadIdx.x;
    int lane = T & 63, fid = T >> 6;
    int jn = fid & 63, kik = fid >> 6;
    int ki = kik & 3, kc = kik >> 2;
    int j  = jn * 16 + (lane & 15);
    int kb = kc * 128 + ki * 32 + (lane >> 4) * 8;
    f16x8 h, lo;
#pragma unroll
    for (int e = 0; e < 8; ++e) {
        int k = kb + e;
        float v = (k <= j) ? Wf[(size_t)j * M_N + k] : 0.0f;
        _Float16 hh = (_Float16)v;
        h[e]  = hh;
        lo[e] = (_Float16)(v - (float)hh);
    }
    size_t off = (size_t)fid * 512 + lane * 8;
    *(f16x8*)(Wph + off) = h;
    *(f16x8*)(Wpl + off) = lo;
}

// ---------------- main fused MFMA kernel: 64 rows x 1024 cols, FULL tile in LDS -------
// Stage the whole 64x1024 fp16 k-tile once (no inner barriers), ONE __syncthreads,
// then a pure MFMA phase over 4 column-groups with acc[4][2] (32 VGPR).
__global__ __launch_bounds__(512) void k_mm(const float* __restrict__ x_star,
                                            const float* __restrict__ pf,
                                            const float* __restrict__ Zst,
                                            const _Float16* __restrict__ Wph,
                                            const _Float16* __restrict__ Wpl,
                                            float* __restrict__ out, int Bq) {
    __shared__ __align__(16) char kls[64 * 2048];   // [row][1024 fp16], 16B-slot swizzled
    __shared__ float red_l[64];
    int tid  = threadIdx.x;
    int slab = blockIdx.x;
    int w = tid >> 6, lane = tid & 63;
    int lrow = lane & 15, kgrp = lane >> 4;

    // staging identity: rows {srow0, srow0+32}, col-group scc (8 cols = 16B) per chunk
    int scc = tid & 15, srow0 = tid >> 4;
    int q0 = slab * 64 + srow0;
    int q1 = q0 + 32;
    int qa = (q0 < Bq) ? q0 : (Bq - 1);
    int qb = (q1 < Bq) ? q1 : (Bq - 1);
    float xa0 = x_star[(size_t)qa * 5 + 0] * pf[0];
    float xa1 = x_star[(size_t)qa * 5 + 1] * pf[1];
    float xa2 = x_star[(size_t)qa * 5 + 2] * pf[2];
    float xa3 = x_star[(size_t)qa * 5 + 3] * pf[3];
    float xa4 = x_star[(size_t)qa * 5 + 4] * pf[4];
    float xb0 = x_star[(size_t)qb * 5 + 0] * pf[0];
    float xb1 = x_star[(size_t)qb * 5 + 1] * pf[1];
    float xb2 = x_star[(size_t)qb * 5 + 2] * pf[2];
    float xb3 = x_star[(size_t)qb * 5 + 3] * pf[3];
    float xb4 = x_star[(size_t)qb * 5 + 4] * pf[4];
    float pv = pf[5];
    if (tid < 64) red_l[tid] = 0.0f;

    int swz = (srow0 & 15) << 4;                 // same for srow0 and srow0+32
    // ---- stage the FULL tile: 8 chunks, no barriers between (disjoint slots) ----
    for (int kc = 0; kc < 8; ++kc) {
        f16x8 h0, h1;
#pragma unroll
        for (int bb = 0; bb < 2; ++bb) {
            int lb = kc * 128 + scc * 8 + bb * 4;
            float z0[4], z1[4], z2[4], z3[4], z4[4];
            *(float4*)z0 = *(const float4*)&Zst[lb];
            *(float4*)z1 = *(const float4*)&Zst[M_N + lb];
            *(float4*)z2 = *(const float4*)&Zst[2 * M_N + lb];
            *(float4*)z3 = *(const float4*)&Zst[3 * M_N + lb];
            *(float4*)z4 = *(const float4*)&Zst[4 * M_N + lb];
#pragma unroll
            for (int e = 0; e < 4; ++e) {
                float dx0 = xa0 - z0[e], dx1 = xa1 - z1[e], dx2 = xa2 - z2[e],
                      dx3 = xa3 - z3[e], dx4 = xa4 - z4[e];
                float d2 = dx0 * dx0 + dx1 * dx1 + dx2 * dx2 + dx3 * dx3 + dx4 * dx4;
                float dd = d2 + 1e-8f;
                float dist = sqrtf(dd);
                float sv = 2.23606798f * dist;
                h0[bb * 4 + e] = (_Float16)(pv * (1.0f + sv + 1.66666667f * dd) * __expf(-sv));
                float ex0 = xb0 - z0[e], ex1 = xb1 - z1[e], ex2 = xb2 - z2[e],
                      ex3 = xb3 - z3[e], ex4 = xb4 - z4[e];
                float e2 = ex0 * ex0 + ex1 * ex1 + ex2 * ex2 + ex3 * ex3 + ex4 * ex4;
                float ee = e2 + 1e-8f;
                float edist = sqrtf(ee);
                float esv = 2.23606798f * edist;
                h1[bb * 4 + e] = (_Float16)(pv * (1.0f + esv + 1.66666667f * ee) * __expf(-esv));
            }
        }
        int cb = kc * 256 + scc * 16;            // byte col offset (16B aligned)
        *(f16x8*)(&kls[srow0 * 2048 + (cb ^ swz)]) = h0;
        *(f16x8*)(&kls[(srow0 + 32) * 2048 + (cb ^ swz)]) = h1;
    }
    __syncthreads();                             // the ONE barrier

    // ---- pure MFMA phase: 4 column groups of 16 jng each ----
    for (int jg = 0; jg < 4; ++jg) {
        f32x4 acc[4][2];
#pragma unroll
        for (int mi = 0; mi < 4; ++mi)
#pragma unroll
            for (int nj = 0; nj < 2; ++nj) acc[mi][nj] = (f32x4)(0.0f);

        int jng_hi = jg * 16 + 8 + ((w + 1) & 7);     // wave's max jng this group
        int jmax_w = jng_hi * 16 + 15;

        for (int kt = 0; kt < 32; ++kt) {
            int kmin = kt * 32;
            if (kmin > jmax_w) break;                 // wave-uniform
            f16x8 A_[4];
#pragma unroll
            for (int mi = 0; mi < 4; ++mi) {
                int row = mi * 16 + lrow;
                int cb  = kt * 64 + kgrp * 16;        // bytes: kt-th 32k chunk + kgrp*8 f16
                A_[mi] = *(const f16x8*)(&kls[row * 2048 + (cb ^ ((row & 15) << 4))]);
            }
#pragma unroll
            for (int nj = 0; nj < 2; ++nj) {
                int jng = jg * 16 + nj * 8 + ((w + nj) & 7);   // balanced interleave
                if (kmin > jng * 16 + 15) continue;            // all-zero W fragment
                size_t fo = ((size_t)(kt * 64 + jng)) * 512 + lane * 8;
                f16x8 Bh = *(const f16x8*)(Wph + fo);
                f16x8 Bl = *(const f16x8*)(Wpl + fo);
#pragma unroll
                for (int mi = 0; mi < 4; ++mi) {
                    acc[mi][nj] = __builtin_amdgcn_mfma_f32_16x16x32_f16(A_[mi], Bh, acc[mi][nj], 0, 0, 0);
                    acc[mi][nj] = __builtin_amdgcn_mfma_f32_16x16x32_f16(A_[mi], Bl, acc[mi][nj], 0, 0, 0);
                }
            }
        }

        // group epilogue: red[row] += y^2 (atomics; no barrier needed between groups)
#pragma unroll
        for (int mi = 0; mi < 4; ++mi) {
#pragma unroll
            for (int q = 0; q < 4; ++q) {
                float s = 0.0f;
#pragma unroll
                for (int nj = 0; nj < 2; ++nj) s = fmaf(acc[mi][nj][q], acc[mi][nj][q], s);
                s += __shfl_xor(s, 1);
                s += __shfl_xor(s, 2);
                s += __shfl_xor(s, 4);
                s += __shfl_xor(s, 8);
                if (lrow == 0) atomicAdd(&red_l[mi * 16 + kgrp * 4 + q], s);
            }
        }
    }
    __syncthreads();
    if (tid < 64) {
        int b = slab * 64 + tid;
        if (b < Bq) out[b] = sqrtf(fmaxf(pv - red_l[tid], 1e-6f));
    }
}

extern "C" void kernel_launch(void* const* d_in, const int* in_sizes, int n_in,
                              void* d_out, int out_size, void* d_ws, size_t ws_size,
                              hipStream_t stream) {
    const float* x_star  = (const float*)d_in[0];
    const float* log_ls  = (const float*)d_in[1];
    const float* log_var = (const float*)d_in[2];
    const float* Z_raw   = (const float*)d_in[3];
    float* out = (float*)d_out;
    int Bq = in_sizes[0] / 5;

    char* ws = (char*)d_ws;
    float*     Kf  = (float*)(ws + OFF_KF);
    float*     Lf  = (float*)(ws + OFF_LF);
    float*     Wf  = (float*)(ws + OFF_WF);
    _Float16*  Wph = (_Float16*)(ws + OFF_WPH);
    _Float16*  Wpl = (_Float16*)(ws + OFF_WPL);
    float*     pf  = (float*)(ws + OFF_PF);
    float*     Zst = (float*)(ws + OFF_ZT);

    k_build<<<4096, 256, 0, stream>>>(log_ls, log_var, Z_raw, Kf, pf, Zst);
    kw_diag<<<64, 512, 0, stream>>>(Kf, Wf, 0);
    for (int kb = 0; kb < NBK - 1; ++kb) {
        int nt = (NBK - 1 - kb) * 2;
        int grid = nt * (nt + 1) / 2 - 2;
        if (grid < 64) grid = 64;                // tiny-grid stall mitigation
        kw_step<<<grid, 256, 0, stream>>>(Kf, Wf, Lf, kb);
    }
    kw_trtri<<<dim3(4, 7), 512, 0, stream>>>(Lf, Wf);
    kw_pack<<<512, 256, 0, stream>>>(Wf, Wph, Wpl);

    int slabs = (Bq + 63) / 64;
    k_mm<<<slabs, 512, 0, stream>>>(x_star, pf, Zst, Wph, Wpl, out, Bq);
}